// Round 1
// baseline (457.619 us; speedup 1.0000x reference)
//
#include <hip/hip_runtime.h>
#include <hip/hip_bf16.h>

typedef __bf16 bf16x8 __attribute__((ext_vector_type(8)));
typedef float f32x4 __attribute__((ext_vector_type(4)));

#define SCALE 0.125f

__device__ __forceinline__ unsigned short f2bf(float f) {
  unsigned int u = __float_as_uint(f);
  u = (u + 0x7fffu + ((u >> 16) & 1u)) >> 16;
  return (unsigned short)u;
}
__device__ __forceinline__ float bf2f(unsigned short s) {
  return __uint_as_float(((unsigned int)s) << 16);
}
__device__ __forceinline__ f32x4 f4zero() {
  f32x4 v; v[0] = 0.f; v[1] = 0.f; v[2] = 0.f; v[3] = 0.f; return v;
}
__device__ __forceinline__ bf16x8 ld8(const unsigned short* p) {
  return *(const bf16x8*)p;
}

// ---------------- prep kernels ----------------

// x -> xb (bf16), new_mem (f32 copy), aux_loss=0
__global__ void cast_copy_x(const float* __restrict__ x, unsigned short* __restrict__ xb,
                            float* __restrict__ newmem, float* __restrict__ aux) {
  long i = (long)blockIdx.x * 256 + threadIdx.x;   // over float4, total 524288
  float4 v = ((const float4*)x)[i];
  ((float4*)newmem)[i] = v;
  ushort4 o; o.x = f2bf(v.x); o.y = f2bf(v.y); o.z = f2bf(v.z); o.w = f2bf(v.w);
  ((ushort4*)xb)[i] = o;
  if (i == 0) aux[0] = 0.f;
}

// mem -> memb bf16
__global__ void cast_mem(const float* __restrict__ mem, unsigned short* __restrict__ memb) {
  long i = (long)blockIdx.x * 256 + threadIdx.x;   // over float4, total 524288
  float4 v = ((const float4*)mem)[i];
  ushort4 o; o.x = f2bf(v.x); o.y = f2bf(v.y); o.z = f2bf(v.z); o.w = f2bf(v.w);
  ((ushort4*)memb)[i] = o;
}

// pos_emb[h,1280+u,d] -> peb[h][u][d] bf16
__global__ void cast_pe(const float* __restrict__ pe, unsigned short* __restrict__ peb) {
  long i = (long)blockIdx.x * 256 + threadIdx.x;   // over float4, total 262144
  int h = (int)(i >> 14);          // 16384 float4 per head
  int rem = (int)(i & 16383);
  const float4* src = (const float4*)(pe + ((long)h * 2304 + 1280) * 64);
  float4 v = src[rem];
  ushort4 o; o.x = f2bf(v.x); o.y = f2bf(v.y); o.z = f2bf(v.z); o.w = f2bf(v.w);
  *(ushort4*)(peb + (long)h * 65536 + (long)rem * 4) = o;
}

// generic f32 (K x N) -> bf16 transpose (N x K)
__global__ void transpose_cast(const float* __restrict__ in, unsigned short* __restrict__ out,
                               int K, int N) {
  __shared__ float tile[64][65];
  int k0 = blockIdx.y * 64, n0 = blockIdx.x * 64;
  int t = threadIdx.x;
  int c = t & 63, r4 = t >> 6;
  for (int rr = r4; rr < 64; rr += 4)
    tile[rr][c] = in[(long)(k0 + rr) * N + n0 + c];
  __syncthreads();
  for (int rr = r4; rr < 64; rr += 4)
    out[(long)(n0 + rr) * K + k0 + c] = f2bf(tile[c][rr]);
}

// conv_w[o][i][kh] -> BcT[o][kh*1024+i] bf16
__global__ void convw_t(const float* __restrict__ cw, unsigned short* __restrict__ BcT) {
  long i = (long)blockIdx.x * 256 + threadIdx.x;   // total 1048576 = o*1024+ii
  int o = (int)(i >> 10), ii = (int)(i & 1023);
  float4 v = *(const float4*)&cw[i * 4];
  unsigned short* base = BcT + (long)o * 4096 + ii;
  base[0]    = f2bf(v.x);
  base[1024] = f2bf(v.y);
  base[2048] = f2bf(v.z);
  base[3072] = f2bf(v.w);
}

// ---------------- generic GEMM: C = A(MxK) @ BT(NxK)^T ----------------
template<int M_REP, bool OUT_F32, bool HAS_BIAS>
__global__ __launch_bounds__(256) void gemm_bt(
    const unsigned short* __restrict__ A, const unsigned short* __restrict__ BT,
    void* __restrict__ Cout, const float* __restrict__ bias,
    int K, int lda, int ldbt, int ldc,
    int zInner, long sAo, long sAi, long sBo, long sBi, long sCo, long sCi) {
  constexpr int BM = 32 * M_REP;
  __shared__ unsigned short As[BM][40];
  __shared__ unsigned short Bs[128][40];
  int z = blockIdx.z;
  int zo = z / zInner, zi = z % zInner;
  A += zo * sAo + zi * sAi;
  BT += zo * sBo + zi * sBi;
  long coff = zo * sCo + zi * sCi;
  int r0 = blockIdx.y * BM;
  int c0 = blockIdx.x * 128;
  int tid = threadIdx.x;
  int lane = tid & 63, wid = tid >> 6;
  int wm = wid >> 1, wn = wid & 1;
  int lr = lane & 15, lg = lane >> 4;

  f32x4 acc[M_REP][4];
  for (int mi = 0; mi < M_REP; ++mi)
    for (int nj = 0; nj < 4; ++nj) acc[mi][nj] = f4zero();

  int nK = K >> 5;
  for (int kt = 0; kt < nK; ++kt) {
    __syncthreads();
    for (int idx = tid; idx < BM * 4; idx += 256) {
      int r = idx >> 2, kc = (idx & 3) * 8;
      *(uint4*)&As[r][kc] = *(const uint4*)&A[(long)(r0 + r) * lda + kt * 32 + kc];
    }
    for (int idx = tid; idx < 512; idx += 256) {
      int r = idx >> 2, kc = (idx & 3) * 8;
      *(uint4*)&Bs[r][kc] = *(const uint4*)&BT[(long)(c0 + r) * ldbt + kt * 32 + kc];
    }
    __syncthreads();
    bf16x8 af[M_REP], bf[4];
    for (int mi = 0; mi < M_REP; ++mi)
      af[mi] = ld8(&As[wm * 16 * M_REP + mi * 16 + lr][lg * 8]);
    for (int nj = 0; nj < 4; ++nj)
      bf[nj] = ld8(&Bs[wn * 64 + nj * 16 + lr][lg * 8]);
    for (int mi = 0; mi < M_REP; ++mi)
      for (int nj = 0; nj < 4; ++nj)
        acc[mi][nj] = __builtin_amdgcn_mfma_f32_16x16x32_bf16(af[mi], bf[nj], acc[mi][nj], 0, 0, 0);
  }
  float* Cf = (float*)Cout;
  unsigned short* Cb = (unsigned short*)Cout;
  for (int mi = 0; mi < M_REP; ++mi)
    for (int nj = 0; nj < 4; ++nj)
      for (int j = 0; j < 4; ++j) {
        int r = r0 + wm * 16 * M_REP + mi * 16 + lg * 4 + j;
        int c = c0 + wn * 64 + nj * 16 + lr;
        float v = acc[mi][nj][j];
        if (HAS_BIAS) v += bias[c];
        long off = coff + (long)r * ldc + c;
        if (OUT_F32) Cf[off] = v; else Cb[off] = f2bf(v);
      }
}

// ---------------- attention ----------------
// grid (8 q-tiles, 16 heads, 2 batch), 512 threads (8 waves, 16 q-rows each)
__global__ __launch_bounds__(512) void attn_kernel(
    const unsigned short* __restrict__ qkv,   // [2048][3072] bf16: q|k|v
    const unsigned short* __restrict__ QP,    // [b][h][r][u] bf16
    unsigned short* __restrict__ obf) {       // [2048][1024] bf16
  int rt = blockIdx.x, h = blockIdx.y, b = blockIdx.z;
  int tid = threadIdx.x;
  int lane = tid & 63, w = tid >> 6;
  int lr = lane & 15, lg = lane >> 4;
  int r0 = rt * 128;

  __shared__ unsigned short KVs[128][72];          // K tile [cx][d]; reused as V [64][136]
  __shared__ unsigned short Ps[8][16][136];        // per-wave P tile

  // q fragments (stay in regs over all k-tiles)
  bf16x8 aq0, aq1;
  {
    const unsigned short* qrow = qkv + ((long)(b * 1024 + r0 + w * 16 + lr)) * 3072 + h * 64;
    aq0 = ld8(qrow + lg * 8);
    aq1 = ld8(qrow + 32 + lg * 8);
  }
  float m[4], lsum[4];
  f32x4 acc_o[4];
  for (int j = 0; j < 4; ++j) { m[j] = -1e30f; lsum[j] = 0.f; }
  for (int nj = 0; nj < 4; ++nj) acc_o[nj] = f4zero();

  const unsigned short* kbase = qkv + (long)b * 1024 * 3072 + 1024 + h * 64;
  const unsigned short* vbase = qkv + (long)b * 1024 * 3072 + 2048 + h * 64;
  const unsigned short* qpb = QP + ((long)(b * 16 + h)) * 1024 * 1024;
  int rg = r0 + w * 16 + lg * 4;   // + j = global q row

  for (int kt = 0; kt < 8; ++kt) {
    int c0 = kt * 128;
    __syncthreads();
    // stage K tile 128x64
    for (int idx = tid; idx < 1024; idx += 512) {
      int r = idx >> 3, c = (idx & 7) * 8;
      *(uint4*)&KVs[r][c] = *(const uint4*)&kbase[(long)(c0 + r) * 3072 + c];
    }
    __syncthreads();
    // S = q @ k^T
    f32x4 accs[8];
    for (int nj = 0; nj < 8; ++nj) {
      accs[nj] = f4zero();
      bf16x8 bk0 = ld8(&KVs[nj * 16 + lr][lg * 8]);
      bf16x8 bk1 = ld8(&KVs[nj * 16 + lr][32 + lg * 8]);
      accs[nj] = __builtin_amdgcn_mfma_f32_16x16x32_bf16(aq0, bk0, accs[nj], 0, 0, 0);
      accs[nj] = __builtin_amdgcn_mfma_f32_16x16x32_bf16(aq1, bk1, accs[nj], 0, 0, 0);
    }
    // epilogue: rel-pos gather + online softmax
    float sv[8][4];
    float tmax[4] = {-1e30f, -1e30f, -1e30f, -1e30f};
    for (int nj = 0; nj < 8; ++nj) {
      int cx = c0 + nj * 16 + lr;
      for (int j = 0; j < 4; ++j) {
        int r = rg + j;
        float s = accs[nj][j];
        int u = 1023 + cx - r;
        if (u < 1024) s += bf2f(qpb[(long)r * 1024 + u]);
        s *= SCALE;
        sv[nj][j] = s;
        tmax[j] = fmaxf(tmax[j], s);
      }
    }
    for (int d = 1; d < 16; d <<= 1)
      for (int j = 0; j < 4; ++j) tmax[j] = fmaxf(tmax[j], __shfl_xor(tmax[j], d, 64));
    float sc[4], rsum[4];
    for (int j = 0; j < 4; ++j) {
      float mn = fmaxf(m[j], tmax[j]);
      sc[j] = __expf(m[j] - mn);
      m[j] = mn;
      rsum[j] = 0.f;
    }
    for (int nj = 0; nj < 8; ++nj)
      for (int j = 0; j < 4; ++j) {
        float p = __expf(sv[nj][j] - m[j]);
        rsum[j] += p;
        Ps[w][lg * 4 + j][nj * 16 + lr] = f2bf(p);
      }
    for (int d = 1; d < 16; d <<= 1)
      for (int j = 0; j < 4; ++j) rsum[j] += __shfl_xor(rsum[j], d, 64);
    for (int j = 0; j < 4; ++j) lsum[j] = lsum[j] * sc[j] + rsum[j];
    for (int nj = 0; nj < 4; ++nj)
      for (int j = 0; j < 4; ++j) acc_o[nj][j] *= sc[j];
    // stage V tile transposed into same LDS: Vs[d][cx]
    __syncthreads();
    unsigned short (*Vs)[136] = (unsigned short (*)[136]) & KVs[0][0];
    for (int idx = tid; idx < 1024; idx += 512) {
      int r = idx >> 3, c = (idx & 7) * 8;   // r=cx, c=d0
      uint4 tv = *(const uint4*)&vbase[(long)(c0 + r) * 3072 + c];
      const unsigned short* ts = (const unsigned short*)&tv;
      for (int i2 = 0; i2 < 8; ++i2) Vs[c + i2][r] = ts[i2];
    }
    __syncthreads();
    // O += P @ V
    for (int ks = 0; ks < 4; ++ks) {
      bf16x8 ap = ld8(&Ps[w][lr][ks * 32 + lg * 8]);
      for (int nj = 0; nj < 4; ++nj) {
        bf16x8 bv = ld8(&Vs[nj * 16 + lr][ks * 32 + lg * 8]);
        acc_o[nj] = __builtin_amdgcn_mfma_f32_16x16x32_bf16(ap, bv, acc_o[nj], 0, 0, 0);
      }
    }
  }
  // write out tile
  for (int nj = 0; nj < 4; ++nj)
    for (int j = 0; j < 4; ++j) {
      float v = acc_o[nj][j] / lsum[j];
      obf[((long)(b * 1024 + rg + j)) * 1024 + h * 64 + nj * 16 + lr] = f2bf(v);
    }
}

// ---------------- launcher ----------------
extern "C" void kernel_launch(void* const* d_in, const int* in_sizes, int n_in,
                              void* d_out, int out_size, void* d_ws, size_t ws_size,
                              hipStream_t stream) {
  const float* x       = (const float*)d_in[0];
  const float* mem     = (const float*)d_in[1];
  const float* pos_emb = (const float*)d_in[3];
  const float* Wq      = (const float*)d_in[5];
  const float* Wkv     = (const float*)d_in[6];
  const float* Wo      = (const float*)d_in[7];
  const float* bo      = (const float*)d_in[8];
  const float* conv_w  = (const float*)d_in[9];
  const float* conv_b  = (const float*)d_in[10];
  float* out = (float*)d_out;

  char* ws = (char*)d_ws;
  unsigned short* xb   = (unsigned short*)(ws + 0);         // 4 MB
  unsigned short* WbT  = (unsigned short*)(ws + 4194304);   // 6 MB  [3072][1024]
  unsigned short* qkvb = (unsigned short*)(ws + 10485760);  // 12 MB [2048][3072]
  unsigned short* peb  = (unsigned short*)(ws + 23068672);  // 2 MB  [16][1024][64]
  unsigned short* obf  = (unsigned short*)(ws + 25165824);  // 4 MB  [2048][1024]
  unsigned short* WoT  = (unsigned short*)(ws + 29360128);  // 2 MB  [1024][1024]
  unsigned short* memb = (unsigned short*)(ws + 31457280);  // 4 MB  [512][4096]
  unsigned short* BcT  = (unsigned short*)(ws + 35651584);  // 8 MB  [1024][4096]
  unsigned short* QPbf = (unsigned short*)(ws + 44040192);  // 64 MB [2][16][1024][1024]

  float* logits   = out;                // 2097152
  float* new_mem  = out + 2097152;      // 2097152
  float* new_cmem = out + 4194304;      // 524288
  float* aux      = out + 4718592;      // 1

  // prep
  cast_copy_x<<<2048, 256, 0, stream>>>(x, xb, new_mem, aux);
  cast_mem<<<2048, 256, 0, stream>>>(mem, memb);
  cast_pe<<<1024, 256, 0, stream>>>(pos_emb, peb);
  transpose_cast<<<dim3(16, 16), 256, 0, stream>>>(Wq, WbT, 1024, 1024);
  transpose_cast<<<dim3(32, 16), 256, 0, stream>>>(Wkv, WbT + 1048576, 1024, 2048);
  transpose_cast<<<dim3(16, 16), 256, 0, stream>>>(Wo, WoT, 1024, 1024);
  convw_t<<<4096, 256, 0, stream>>>(conv_w, BcT);

  // qkv = xb @ WbT^T  (2048 x 3072 x 1024)
  gemm_bt<4, false, false><<<dim3(24, 16, 1), 256, 0, stream>>>(
      xb, WbT, qkvb, nullptr, 1024, 1024, 1024, 3072, 1, 0, 0, 0, 0, 0, 0);

  // QP[b,h] = q[b,h] @ peb[h]^T  (batched 32 x (1024 x 1024 x 64))
  gemm_bt<4, false, false><<<dim3(8, 8, 32), 256, 0, stream>>>(
      qkvb, peb, QPbf, nullptr, 64, 3072, 64, 1024,
      16, 3145728, 64, 0, 65536, 16777216, 1048576);

  // attention
  attn_kernel<<<dim3(8, 16, 2), 512, 0, stream>>>(qkvb, QPbf, obf);

  // logits = obf @ WoT^T + bo  (2048 x 1024 x 1024)
  gemm_bt<4, true, true><<<dim3(8, 16, 1), 256, 0, stream>>>(
      obf, WoT, logits, bo, 1024, 1024, 1024, 1024, 1, 0, 0, 0, 0, 0, 0);

  // new_cmem = memb(512x4096) @ BcT^T + conv_b  (512 x 1024 x 4096)
  gemm_bt<2, true, true><<<dim3(8, 8, 1), 256, 0, stream>>>(
      memb, BcT, new_cmem, conv_b, 4096, 4096, 4096, 1024, 1, 0, 0, 0, 0, 0, 0);
}

// Round 2
// 332.296 us; speedup vs baseline: 1.3771x; 1.3771x over previous
//
#include <hip/hip_runtime.h>
#include <hip/hip_bf16.h>

typedef __bf16 bf16x8 __attribute__((ext_vector_type(8)));
typedef float f32x4 __attribute__((ext_vector_type(4)));

#define SCALE 0.125f

typedef __attribute__((address_space(1))) const unsigned int gas_u32;
typedef __attribute__((address_space(3))) unsigned int las_u32;

__device__ __forceinline__ void gload16(const void* g, void* l) {
  __builtin_amdgcn_global_load_lds((gas_u32*)g, (las_u32*)l, 16, 0, 0);
}

__device__ __forceinline__ unsigned short f2bf(float f) {
  unsigned int u = __float_as_uint(f);
  u = (u + 0x7fffu + ((u >> 16) & 1u)) >> 16;
  return (unsigned short)u;
}
__device__ __forceinline__ float bf2f(unsigned short s) {
  return __uint_as_float(((unsigned int)s) << 16);
}
__device__ __forceinline__ f32x4 f4zero() {
  f32x4 v; v[0] = 0.f; v[1] = 0.f; v[2] = 0.f; v[3] = 0.f; return v;
}
__device__ __forceinline__ bf16x8 ld8(const unsigned short* p) {
  return *(const bf16x8*)p;
}

// ---------------- prep kernels ----------------

__global__ void cast_copy_x(const float* __restrict__ x, unsigned short* __restrict__ xb,
                            float* __restrict__ newmem, float* __restrict__ aux) {
  long i = (long)blockIdx.x * 256 + threadIdx.x;   // over float4, total 524288
  float4 v = ((const float4*)x)[i];
  ((float4*)newmem)[i] = v;
  ushort4 o; o.x = f2bf(v.x); o.y = f2bf(v.y); o.z = f2bf(v.z); o.w = f2bf(v.w);
  ((ushort4*)xb)[i] = o;
  if (i == 0) aux[0] = 0.f;
}

__global__ void cast_mem(const float* __restrict__ mem, unsigned short* __restrict__ memb) {
  long i = (long)blockIdx.x * 256 + threadIdx.x;   // over float4, total 524288
  float4 v = ((const float4*)mem)[i];
  ushort4 o; o.x = f2bf(v.x); o.y = f2bf(v.y); o.z = f2bf(v.z); o.w = f2bf(v.w);
  ((ushort4*)memb)[i] = o;
}

// pos_emb[h,1280+u,d] -> peb[h][u][d] bf16
__global__ void cast_pe(const float* __restrict__ pe, unsigned short* __restrict__ peb) {
  long i = (long)blockIdx.x * 256 + threadIdx.x;   // over float4, total 262144
  int h = (int)(i >> 14);
  int rem = (int)(i & 16383);
  const float4* src = (const float4*)(pe + ((long)h * 2304 + 1280) * 64);
  float4 v = src[rem];
  ushort4 o; o.x = f2bf(v.x); o.y = f2bf(v.y); o.z = f2bf(v.z); o.w = f2bf(v.w);
  *(ushort4*)(peb + (long)h * 65536 + (long)rem * 4) = o;
}

// generic f32 (K x N) -> bf16 transpose (N x K)
__global__ void transpose_cast(const float* __restrict__ in, unsigned short* __restrict__ out,
                               int K, int N) {
  __shared__ float tile[64][65];
  int k0 = blockIdx.y * 64, n0 = blockIdx.x * 64;
  int t = threadIdx.x;
  int c = t & 63, r4 = t >> 6;
  for (int rr = r4; rr < 64; rr += 4)
    tile[rr][c] = in[(long)(k0 + rr) * N + n0 + c];
  __syncthreads();
  for (int rr = r4; rr < 64; rr += 4)
    out[(long)(n0 + rr) * K + k0 + c] = f2bf(tile[c][rr]);
}

// conv_w[o][i][kh] -> BcT[o][kh*1024+i] bf16
__global__ void convw_t(const float* __restrict__ cw, unsigned short* __restrict__ BcT) {
  long i = (long)blockIdx.x * 256 + threadIdx.x;   // total 1048576 = o*1024+ii
  int o = (int)(i >> 10), ii = (int)(i & 1023);
  float4 v = *(const float4*)&cw[i * 4];
  unsigned short* base = BcT + (long)o * 4096 + ii;
  base[0]    = f2bf(v.x);
  base[1024] = f2bf(v.y);
  base[2048] = f2bf(v.z);
  base[3072] = f2bf(v.w);
}

// sum 8 split-K partials + bias -> out (512x1024 f32)
__global__ void splitk_reduce_bias(const float* __restrict__ part,
                                   const float* __restrict__ bias,
                                   float* __restrict__ out) {
  int i = blockIdx.x * 256 + threadIdx.x;   // over float4, total 131072
  float4 a = ((const float4*)part)[i];
  for (int s = 1; s < 8; ++s) {
    float4 b = ((const float4*)(part + (long)s * 524288))[i];
    a.x += b.x; a.y += b.y; a.z += b.z; a.w += b.w;
  }
  float4 bb = *(const float4*)&bias[(i * 4) & 1023];
  a.x += bb.x; a.y += bb.y; a.z += bb.z; a.w += bb.w;
  ((float4*)out)[i] = a;
}

// ---------------- generic GEMM: C = A(MxK) @ BT(NxK)^T ----------------
// global_load_lds (16B) staging, linear LDS dest, XOR-swizzled 16B slots:
// LDS row r, slot s (of 4) holds global col-group g = s ^ ((r>>1)&3).
template<int M_REP, bool OUT_F32, bool HAS_BIAS>
__global__ __launch_bounds__(256) void gemm_bt(
    const unsigned short* __restrict__ A, const unsigned short* __restrict__ BT,
    void* __restrict__ Cout, const float* __restrict__ bias,
    int K, int lda, int ldbt, int ldc,
    int zInner, long sAo, long sAi, long sBo, long sBi, long sCo, long sCi) {
  constexpr int BM = 32 * M_REP;
  constexpr int ACH = BM / 16;          // 1KB chunks in As
  __shared__ unsigned short As[BM * 32];
  __shared__ unsigned short Bs[128 * 32];
  int z = blockIdx.z;
  int zo = z / zInner, zi = z % zInner;
  A += zo * sAo + zi * sAi;
  BT += zo * sBo + zi * sBi;
  long coff = zo * sCo + zi * sCi;
  int r0 = blockIdx.y * BM;
  int c0 = blockIdx.x * 128;
  int tid = threadIdx.x;
  int lane = tid & 63, wid = tid >> 6;
  int wm = wid >> 1, wn = wid & 1;
  int lr = lane & 15, lg = lane >> 4;
  // staging lane constants: within a 16-row chunk, lane covers row lane>>2,
  // global col-group g = (lane&3) ^ ((lane>>3)&3)  (inverse swizzle at source)
  int srow = lane >> 2;
  int sg8 = (((lane & 3) ^ ((lane >> 3) & 3)) * 8);

  f32x4 acc[M_REP][4];
  for (int mi = 0; mi < M_REP; ++mi)
    for (int nj = 0; nj < 4; ++nj) acc[mi][nj] = f4zero();

  int nK = K >> 5;
  for (int kt = 0; kt < nK; ++kt) {
    __syncthreads();
    for (int c = wid; c < ACH + 8; c += 4) {
      if (c < ACH) {
        int row = c * 16 + srow;
        gload16(&A[(long)(r0 + row) * lda + kt * 32 + sg8], As + c * 512);
      } else {
        int cb = c - ACH;
        int row = cb * 16 + srow;
        gload16(&BT[(long)(c0 + row) * ldbt + kt * 32 + sg8], Bs + cb * 512);
      }
    }
    __syncthreads();
    bf16x8 af[M_REP], bfr[4];
    for (int mi = 0; mi < M_REP; ++mi) {
      int row = wm * (16 * M_REP) + mi * 16 + lr;
      af[mi] = ld8(&As[row * 32 + ((lg ^ ((row >> 1) & 3)) * 8)]);
    }
    for (int nj = 0; nj < 4; ++nj) {
      int row = wn * 64 + nj * 16 + lr;
      bfr[nj] = ld8(&Bs[row * 32 + ((lg ^ ((row >> 1) & 3)) * 8)]);
    }
    for (int mi = 0; mi < M_REP; ++mi)
      for (int nj = 0; nj < 4; ++nj)
        acc[mi][nj] = __builtin_amdgcn_mfma_f32_16x16x32_bf16(af[mi], bfr[nj], acc[mi][nj], 0, 0, 0);
  }
  float* Cf = (float*)Cout;
  unsigned short* Cb = (unsigned short*)Cout;
  for (int mi = 0; mi < M_REP; ++mi)
    for (int nj = 0; nj < 4; ++nj)
      for (int j = 0; j < 4; ++j) {
        int r = r0 + wm * (16 * M_REP) + mi * 16 + lg * 4 + j;
        int c = c0 + wn * 64 + nj * 16 + lr;
        float v = acc[mi][nj][j];
        if (HAS_BIAS) v += bias[c];
        long off = coff + (long)r * ldc + c;
        if (OUT_F32) Cf[off] = v; else Cb[off] = f2bf(v);
      }
}

// ---------------- attention ----------------
// grid (8 q-tiles, 16 heads, 2 batch), 512 threads (8 waves, 16 q-rows each)
__global__ __launch_bounds__(512) void attn_kernel(
    const unsigned short* __restrict__ qkv,   // [2048][3072] bf16: q|k|v
    const unsigned short* __restrict__ QP,    // [b][h][r][u] bf16
    unsigned short* __restrict__ obf) {       // [2048][1024] bf16
  int rt = blockIdx.x, h = blockIdx.y, b = blockIdx.z;
  int tid = threadIdx.x;
  int lane = tid & 63, w = tid >> 6;
  int lr = lane & 15, lg = lane >> 4;
  int r0 = rt * 128;

  __shared__ unsigned short KVs[128][72];          // K tile [cx][d]; reused as V [64][136]
  __shared__ unsigned short Ps[8][16][136];        // per-wave P tile

  bf16x8 aq0, aq1;
  {
    const unsigned short* qrow = qkv + ((long)(b * 1024 + r0 + w * 16 + lr)) * 3072 + h * 64;
    aq0 = ld8(qrow + lg * 8);
    aq1 = ld8(qrow + 32 + lg * 8);
  }
  float m[4], lsum[4];
  f32x4 acc_o[4];
  for (int j = 0; j < 4; ++j) { m[j] = -1e30f; lsum[j] = 0.f; }
  for (int nj = 0; nj < 4; ++nj) acc_o[nj] = f4zero();

  const unsigned short* kbase = qkv + (long)b * 1024 * 3072 + 1024 + h * 64;
  const unsigned short* vbase = qkv + (long)b * 1024 * 3072 + 2048 + h * 64;
  const unsigned short* qpb = QP + ((long)(b * 16 + h)) * 1024 * 1024;
  int rg = r0 + w * 16 + lg * 4;   // + j = global q row

  for (int kt = 0; kt < 8; ++kt) {
    int c0 = kt * 128;
    __syncthreads();
    for (int idx = tid; idx < 1024; idx += 512) {
      int r = idx >> 3, c = (idx & 7) * 8;
      *(uint4*)&KVs[r][c] = *(const uint4*)&kbase[(long)(c0 + r) * 3072 + c];
    }
    __syncthreads();
    f32x4 accs[8];
    for (int nj = 0; nj < 8; ++nj) {
      accs[nj] = f4zero();
      bf16x8 bk0 = ld8(&KVs[nj * 16 + lr][lg * 8]);
      bf16x8 bk1 = ld8(&KVs[nj * 16 + lr][32 + lg * 8]);
      accs[nj] = __builtin_amdgcn_mfma_f32_16x16x32_bf16(aq0, bk0, accs[nj], 0, 0, 0);
      accs[nj] = __builtin_amdgcn_mfma_f32_16x16x32_bf16(aq1, bk1, accs[nj], 0, 0, 0);
    }
    float sv[8][4];
    float tmax[4] = {-1e30f, -1e30f, -1e30f, -1e30f};
    for (int nj = 0; nj < 8; ++nj) {
      int cx = c0 + nj * 16 + lr;
      for (int j = 0; j < 4; ++j) {
        int r = rg + j;
        float s = accs[nj][j];
        int u = 1023 + cx - r;
        if (u < 1024) s += bf2f(qpb[(long)r * 1024 + u]);
        s *= SCALE;
        sv[nj][j] = s;
        tmax[j] = fmaxf(tmax[j], s);
      }
    }
    for (int d = 1; d < 16; d <<= 1)
      for (int j = 0; j < 4; ++j) tmax[j] = fmaxf(tmax[j], __shfl_xor(tmax[j], d, 64));
    float sc[4], rsum[4];
    for (int j = 0; j < 4; ++j) {
      float mn = fmaxf(m[j], tmax[j]);
      sc[j] = __expf(m[j] - mn);
      m[j] = mn;
      rsum[j] = 0.f;
    }
    for (int nj = 0; nj < 8; ++nj)
      for (int j = 0; j < 4; ++j) {
        float p = __expf(sv[nj][j] - m[j]);
        rsum[j] += p;
        Ps[w][lg * 4 + j][nj * 16 + lr] = f2bf(p);
      }
    for (int d = 1; d < 16; d <<= 1)
      for (int j = 0; j < 4; ++j) rsum[j] += __shfl_xor(rsum[j], d, 64);
    for (int j = 0; j < 4; ++j) lsum[j] = lsum[j] * sc[j] + rsum[j];
    for (int nj = 0; nj < 4; ++nj)
      for (int j = 0; j < 4; ++j) acc_o[nj][j] *= sc[j];
    __syncthreads();
    unsigned short (*Vs)[136] = (unsigned short (*)[136]) & KVs[0][0];
    for (int idx = tid; idx < 1024; idx += 512) {
      int r = idx >> 3, c = (idx & 7) * 8;   // r=cx, c=d0
      uint4 tv = *(const uint4*)&vbase[(long)(c0 + r) * 3072 + c];
      const unsigned short* ts = (const unsigned short*)&tv;
      for (int i2 = 0; i2 < 8; ++i2) Vs[c + i2][r] = ts[i2];
    }
    __syncthreads();
    for (int ks = 0; ks < 4; ++ks) {
      bf16x8 ap = ld8(&Ps[w][lr][ks * 32 + lg * 8]);
      for (int nj = 0; nj < 4; ++nj) {
        bf16x8 bv = ld8(&Vs[nj * 16 + lr][ks * 32 + lg * 8]);
        acc_o[nj] = __builtin_amdgcn_mfma_f32_16x16x32_bf16(ap, bv, acc_o[nj], 0, 0, 0);
      }
    }
  }
  for (int nj = 0; nj < 4; ++nj)
    for (int j = 0; j < 4; ++j) {
      float v = acc_o[nj][j] / lsum[j];
      obf[((long)(b * 1024 + rg + j)) * 1024 + h * 64 + nj * 16 + lr] = f2bf(v);
    }
}

// ---------------- launcher ----------------
extern "C" void kernel_launch(void* const* d_in, const int* in_sizes, int n_in,
                              void* d_out, int out_size, void* d_ws, size_t ws_size,
                              hipStream_t stream) {
  const float* x       = (const float*)d_in[0];
  const float* mem     = (const float*)d_in[1];
  const float* pos_emb = (const float*)d_in[3];
  const float* Wq      = (const float*)d_in[5];
  const float* Wkv     = (const float*)d_in[6];
  const float* Wo      = (const float*)d_in[7];
  const float* bo      = (const float*)d_in[8];
  const float* conv_w  = (const float*)d_in[9];
  const float* conv_b  = (const float*)d_in[10];
  float* out = (float*)d_out;

  char* ws = (char*)d_ws;
  unsigned short* xb   = (unsigned short*)(ws + 0);         // 4 MB
  unsigned short* WbT  = (unsigned short*)(ws + 4194304);   // 6 MB  [3072][1024]
  unsigned short* qkvb = (unsigned short*)(ws + 10485760);  // 12 MB [2048][3072]
  unsigned short* peb  = (unsigned short*)(ws + 23068672);  // 2 MB  [16][1024][64]
  unsigned short* obf  = (unsigned short*)(ws + 25165824);  // 4 MB  [2048][1024]
  unsigned short* WoT  = (unsigned short*)(ws + 29360128);  // 2 MB  [1024][1024]
  unsigned short* memb = (unsigned short*)(ws + 31457280);  // 4 MB  [512][4096]
  unsigned short* BcT  = (unsigned short*)(ws + 35651584);  // 8 MB  [1024][4096]
  unsigned short* QPbf = (unsigned short*)(ws + 44040192);  // 64 MB [2][16][1024][1024]
  float* convpart = (float*)(ws + 44040192);                // 16 MB, reuses QP after attn

  float* logits   = out;                // 2097152
  float* new_mem  = out + 2097152;      // 2097152
  float* new_cmem = out + 4194304;      // 524288
  float* aux      = out + 4718592;      // 1

  // prep
  cast_copy_x<<<2048, 256, 0, stream>>>(x, xb, new_mem, aux);
  cast_mem<<<2048, 256, 0, stream>>>(mem, memb);
  cast_pe<<<1024, 256, 0, stream>>>(pos_emb, peb);
  transpose_cast<<<dim3(16, 16), 256, 0, stream>>>(Wq, WbT, 1024, 1024);
  transpose_cast<<<dim3(32, 16), 256, 0, stream>>>(Wkv, WbT + 1048576, 1024, 2048);
  transpose_cast<<<dim3(16, 16), 256, 0, stream>>>(Wo, WoT, 1024, 1024);
  convw_t<<<4096, 256, 0, stream>>>(conv_w, BcT);

  // qkv = xb @ WbT^T  (2048 x 3072 x 1024), BM=64 -> 768 blocks
  gemm_bt<2, false, false><<<dim3(24, 32, 1), 256, 0, stream>>>(
      xb, WbT, qkvb, nullptr, 1024, 1024, 1024, 3072, 1, 0, 0, 0, 0, 0, 0);

  // QP[b,h] = q[b,h] @ peb[h]^T  (batched 32 x (1024 x 1024 x 64)), 2048 blocks
  gemm_bt<4, false, false><<<dim3(8, 8, 32), 256, 0, stream>>>(
      qkvb, peb, QPbf, nullptr, 64, 3072, 64, 1024,
      16, 3145728, 64, 0, 65536, 16777216, 1048576);

  // attention
  attn_kernel<<<dim3(8, 16, 2), 512, 0, stream>>>(qkvb, QPbf, obf);

  // logits = obf @ WoT^T + bo  (2048 x 1024 x 1024), BM=64 -> 256 blocks
  gemm_bt<2, true, true><<<dim3(8, 32, 1), 256, 0, stream>>>(
      obf, WoT, logits, bo, 1024, 1024, 1024, 1024, 1, 0, 0, 0, 0, 0, 0);

  // new_cmem partials: split-K x8 (512 blocks, K=512 each)
  gemm_bt<2, true, false><<<dim3(8, 8, 8), 256, 0, stream>>>(
      memb, BcT, convpart, nullptr, 512, 4096, 4096, 1024,
      1, 512, 0, 512, 0, 524288, 0);
  splitk_reduce_bias<<<512, 256, 0, stream>>>(convpart, conv_b, new_cmem);
}

// Round 5
// 269.918 us; speedup vs baseline: 1.6954x; 1.2311x over previous
//
#include <hip/hip_runtime.h>
#include <hip/hip_bf16.h>

typedef __bf16 bf16x8 __attribute__((ext_vector_type(8)));
typedef float f32x4 __attribute__((ext_vector_type(4)));

#define SCALE 0.125f

typedef __attribute__((address_space(1))) const unsigned int gas_u32;
typedef __attribute__((address_space(3))) unsigned int las_u32;

__device__ __forceinline__ void gload16(const void* g, void* l) {
  __builtin_amdgcn_global_load_lds((gas_u32*)g, (las_u32*)l, 16, 0, 0);
}

__device__ __forceinline__ unsigned short f2bf(float f) {
  unsigned int u = __float_as_uint(f);
  u = (u + 0x7fffu + ((u >> 16) & 1u)) >> 16;
  return (unsigned short)u;
}
__device__ __forceinline__ float bf2f(unsigned short s) {
  return __uint_as_float(((unsigned int)s) << 16);
}
__device__ __forceinline__ f32x4 f4zero() {
  f32x4 v; v[0] = 0.f; v[1] = 0.f; v[2] = 0.f; v[3] = 0.f; return v;
}
__device__ __forceinline__ bf16x8 ld8(const unsigned short* p) {
  return *(const bf16x8*)p;
}

// ---------------- prep kernels ----------------

// merged: x -> xb/new_mem/aux, mem -> memb
__global__ void cast_x_mem(const float* __restrict__ x, const float* __restrict__ mem,
                           unsigned short* __restrict__ xb, unsigned short* __restrict__ memb,
                           float* __restrict__ newmem, float* __restrict__ aux) {
  long i = (long)blockIdx.x * 256 + threadIdx.x;   // over float4, total 1048576
  if (i < 524288) {
    float4 v = ((const float4*)x)[i];
    ((float4*)newmem)[i] = v;
    ushort4 o; o.x = f2bf(v.x); o.y = f2bf(v.y); o.z = f2bf(v.z); o.w = f2bf(v.w);
    ((ushort4*)xb)[i] = o;
    if (i == 0) aux[0] = 0.f;
  } else {
    long j = i - 524288;
    float4 v = ((const float4*)mem)[j];
    ushort4 o; o.x = f2bf(v.x); o.y = f2bf(v.y); o.z = f2bf(v.z); o.w = f2bf(v.w);
    ((ushort4*)memb)[j] = o;
  }
}

// pos_emb[h,1280+u,d] -> peb[h][u][d] bf16
__global__ void cast_pe(const float* __restrict__ pe, unsigned short* __restrict__ peb) {
  long i = (long)blockIdx.x * 256 + threadIdx.x;   // over float4, total 262144
  int h = (int)(i >> 14);
  int rem = (int)(i & 16383);
  const float4* src = (const float4*)(pe + ((long)h * 2304 + 1280) * 64);
  float4 v = src[rem];
  ushort4 o; o.x = f2bf(v.x); o.y = f2bf(v.y); o.z = f2bf(v.z); o.w = f2bf(v.w);
  *(ushort4*)(peb + (long)h * 65536 + (long)rem * 4) = o;
}

// merged 3-way f32 (K x N) -> bf16 transpose (N x K): Wq, Wkv, Wo
__global__ void transpose3(const float* __restrict__ Wq, const float* __restrict__ Wkv,
                           const float* __restrict__ Wo,
                           unsigned short* __restrict__ WbT, unsigned short* __restrict__ WoT) {
  __shared__ float tile[64][65];
  int bx = blockIdx.x;
  const float* in; unsigned short* out; int N, bxl;
  if (bx < 16)      { in = Wq;  out = WbT;           N = 1024; bxl = bx; }
  else if (bx < 48) { in = Wkv; out = WbT + 1048576; N = 2048; bxl = bx - 16; }
  else              { in = Wo;  out = WoT;           N = 1024; bxl = bx - 48; }
  int k0 = blockIdx.y * 64, n0 = bxl * 64;
  int t = threadIdx.x;
  int c = t & 63, r4 = t >> 6;
  for (int rr = r4; rr < 64; rr += 4)
    tile[rr][c] = in[(long)(k0 + rr) * N + n0 + c];
  __syncthreads();
  for (int rr = r4; rr < 64; rr += 4)
    out[(long)(n0 + rr) * 1024 + k0 + c] = f2bf(tile[c][rr]);
}

// conv_w[o][i][kh] -> BcT[o][kh*1024+i] bf16
__global__ void convw_t(const float* __restrict__ cw, unsigned short* __restrict__ BcT) {
  long i = (long)blockIdx.x * 256 + threadIdx.x;   // total 1048576 = o*1024+ii
  int o = (int)(i >> 10), ii = (int)(i & 1023);
  float4 v = *(const float4*)&cw[i * 4];
  unsigned short* base = BcT + (long)o * 4096 + ii;
  base[0]    = f2bf(v.x);
  base[1024] = f2bf(v.y);
  base[2048] = f2bf(v.z);
  base[3072] = f2bf(v.w);
}

// qkvb v-section -> Vt[b][h][d][t] bf16
__global__ void vt_prep(const unsigned short* __restrict__ qkvb, unsigned short* __restrict__ Vt) {
  __shared__ unsigned short L[64][72];
  int tt = blockIdx.x, h = blockIdx.y, b = blockIdx.z;
  int t0 = tt * 64;
  int tid = threadIdx.x;
  int row = tid >> 2, ch = tid & 3;
  const unsigned short* src = qkvb + (long)(b * 1024 + t0 + row) * 3072 + 2048 + h * 64;
  *(uint4*)&L[row][ch * 8]       = *(const uint4*)&src[ch * 8];
  *(uint4*)&L[row][(ch + 4) * 8] = *(const uint4*)&src[(ch + 4) * 8];
  __syncthreads();
  int d = tid >> 2, tch = tid & 3;
  unsigned short* dst = Vt + ((long)((b * 16 + h) * 64 + d)) * 1024 + t0;
  for (int s = tch; s < 8; s += 4) {
    unsigned short tmp[8];
    for (int i = 0; i < 8; ++i) tmp[i] = L[s * 8 + i][d];
    *(uint4*)&dst[s * 8] = *(const uint4*)tmp;
  }
}

// sum 8 split-K partials + bias -> out (512x1024 f32)
__global__ void splitk_reduce_bias(const float* __restrict__ part,
                                   const float* __restrict__ bias,
                                   float* __restrict__ out) {
  int i = blockIdx.x * 256 + threadIdx.x;   // over float4, total 131072
  float4 a = ((const float4*)part)[i];
  for (int s = 1; s < 8; ++s) {
    float4 b = ((const float4*)(part + (long)s * 524288))[i];
    a.x += b.x; a.y += b.y; a.z += b.z; a.w += b.w;
  }
  float4 bb = *(const float4*)&bias[(i * 4) & 1023];
  a.x += bb.x; a.y += bb.y; a.z += bb.z; a.w += bb.w;
  ((float4*)out)[i] = a;
}

// ---------------- generic GEMM: C = A(MxK) @ BT(NxK)^T ----------------
// global_load_lds (16B) staging, linear LDS dest, XOR-swizzled 16B slots.
// SHIFT: write C[r][u] to C[r][u+r-1023] if >= 0 (rel-pos pre-shift).
// SKIP: skip blocks with bx+by < 7 (entire output below the shift band).
template<int M_REP, bool OUT_F32, bool HAS_BIAS, bool SHIFT, bool SKIP>
__global__ __launch_bounds__(256) void gemm_bt(
    const unsigned short* __restrict__ A, const unsigned short* __restrict__ BT,
    void* __restrict__ Cout, const float* __restrict__ bias,
    int K, int lda, int ldbt, int ldc,
    int zInner, long sAo, long sAi, long sBo, long sBi, long sCo, long sCi) {
  if (SKIP && (int)(blockIdx.x + blockIdx.y) < 7) return;
  constexpr int BM = 32 * M_REP;
  constexpr int ACH = BM / 16;          // 1KB chunks in As
  __shared__ unsigned short As[BM * 32];
  __shared__ unsigned short Bs[128 * 32];
  int z = blockIdx.z;
  int zo = z / zInner, zi = z % zInner;
  A += zo * sAo + zi * sAi;
  BT += zo * sBo + zi * sBi;
  long coff = zo * sCo + zi * sCi;
  int r0 = blockIdx.y * BM;
  int c0 = blockIdx.x * 128;
  int tid = threadIdx.x;
  int lane = tid & 63, wid = tid >> 6;
  int wm = wid >> 1, wn = wid & 1;
  int lr = lane & 15, lg = lane >> 4;
  int srow = lane >> 2;
  int sg8 = (((lane & 3) ^ ((lane >> 3) & 3)) * 8);

  f32x4 acc[M_REP][4];
  for (int mi = 0; mi < M_REP; ++mi)
    for (int nj = 0; nj < 4; ++nj) acc[mi][nj] = f4zero();

  int nK = K >> 5;
  for (int kt = 0; kt < nK; ++kt) {
    __syncthreads();
    for (int c = wid; c < ACH + 8; c += 4) {
      if (c < ACH) {
        int row = c * 16 + srow;
        gload16(&A[(long)(r0 + row) * lda + kt * 32 + sg8], As + c * 512);
      } else {
        int cb = c - ACH;
        int row = cb * 16 + srow;
        gload16(&BT[(long)(c0 + row) * ldbt + kt * 32 + sg8], Bs + cb * 512);
      }
    }
    __syncthreads();
    bf16x8 af[M_REP], bfr[4];
    for (int mi = 0; mi < M_REP; ++mi) {
      int row = wm * (16 * M_REP) + mi * 16 + lr;
      af[mi] = ld8(&As[row * 32 + ((lg ^ ((row >> 1) & 3)) * 8)]);
    }
    for (int nj = 0; nj < 4; ++nj) {
      int row = wn * 64 + nj * 16 + lr;
      bfr[nj] = ld8(&Bs[row * 32 + ((lg ^ ((row >> 1) & 3)) * 8)]);
    }
    for (int mi = 0; mi < M_REP; ++mi)
      for (int nj = 0; nj < 4; ++nj)
        acc[mi][nj] = __builtin_amdgcn_mfma_f32_16x16x32_bf16(af[mi], bfr[nj], acc[mi][nj], 0, 0, 0);
  }
  float* Cf = (float*)Cout;
  unsigned short* Cb = (unsigned short*)Cout;
  for (int mi = 0; mi < M_REP; ++mi)
    for (int nj = 0; nj < 4; ++nj)
      for (int j = 0; j < 4; ++j) {
        int r = r0 + wm * (16 * M_REP) + mi * 16 + lg * 4 + j;
        int c = c0 + wn * 64 + nj * 16 + lr;
        float v = acc[mi][nj][j];
        if (HAS_BIAS) v += bias[c];
        if (SHIFT) {
          int cx = c + r - 1023;
          if (cx >= 0) Cb[coff + (long)r * ldc + cx] = f2bf(v);
        } else {
          long off = coff + (long)r * ldc + c;
          if (OUT_F32) Cf[off] = v; else Cb[off] = f2bf(v);
        }
      }
}

// ---------------- attention ----------------
// grid (16 q-tiles, 16 heads, 2 batch), 256 threads (4 waves, 16 q-rows each)
__global__ __launch_bounds__(256) void attn_kernel(
    const unsigned short* __restrict__ qkv,   // [2048][3072] bf16: q|k|v
    const unsigned short* __restrict__ Vt,    // [b][h][d][1024] bf16
    const unsigned short* __restrict__ QPs,   // [b][h][r][cx] bf16 (pre-shifted, cx<=r valid)
    unsigned short* __restrict__ obf) {       // [2048][1024] bf16
  int rt = blockIdx.x, h = blockIdx.y, b = blockIdx.z;
  int tid = threadIdx.x;
  int lane = tid & 63, w = tid >> 6;
  int lr = lane & 15, lg = lane >> 4;
  int r0 = rt * 64;

  __shared__ unsigned short Ks[64 * 64];   // [cx][d], slot-swizzled
  __shared__ unsigned short Vs[64 * 64];   // [d][cx], slot-swizzled
  __shared__ unsigned short Ps[4][16][72];

  bf16x8 aq0, aq1;
  {
    const unsigned short* qrow = qkv + ((long)(b * 1024 + r0 + w * 16 + lr)) * 3072 + h * 64;
    aq0 = ld8(qrow + lg * 8);
    aq1 = ld8(qrow + 32 + lg * 8);
  }
  float m[4], lsum[4];
  f32x4 acc_o[4];
  for (int j = 0; j < 4; ++j) { m[j] = -1e30f; lsum[j] = 0.f; }
  for (int n = 0; n < 4; ++n) acc_o[n] = f4zero();

  const unsigned short* kbase = qkv + (long)b * 1024 * 3072 + 1024 + h * 64;
  const unsigned short* vtb = Vt + ((long)(b * 16 + h)) * 65536;
  const unsigned short* qpb = QPs + ((long)(b * 16 + h)) * 1048576;
  int rg = r0 + w * 16 + lg * 4;   // + j = global q row

  int srow = (lane >> 3) & 7;   // row within 8-row chunk
  int sslot = lane & 7;         // dest 16B slot within row

  for (int kt = 0; kt < 16; ++kt) {
    int c0 = kt * 64;
    __syncthreads();
    for (int i = 0; i < 2; ++i) {
      int chunk = w * 2 + i;                 // 0..7 (8 rows each)
      int row = chunk * 8 + srow;            // 0..63
      int g = sslot ^ (row & 7);             // inverse swizzle at source
      gload16(&kbase[(long)(c0 + row) * 3072 + g * 8], Ks + chunk * 512);
      gload16(&vtb[(long)row * 1024 + c0 + g * 8], Vs + chunk * 512);
    }
    __syncthreads();
    // QP prefetch (only tiles on/below the diagonal band)
    float qpv[4][4];
    bool anyqp = (kt <= rt);
    if (anyqp) {
      for (int nj = 0; nj < 4; ++nj) {
        int cx = c0 + nj * 16 + lr;
        for (int j = 0; j < 4; ++j) {
          int r = rg + j;
          float v = bf2f(qpb[(long)r * 1024 + cx]);
          qpv[nj][j] = (kt < rt || cx <= r) ? v : 0.f;
        }
      }
    }
    // S = q @ k^T
    f32x4 accs[4];
    for (int nj = 0; nj < 4; ++nj) {
      int row = nj * 16 + lr;
      bf16x8 bk0 = ld8(&Ks[row * 64 + ((lg ^ (row & 7)) * 8)]);
      bf16x8 bk1 = ld8(&Ks[row * 64 + (((4 + lg) ^ (row & 7)) * 8)]);
      accs[nj] = f4zero();
      accs[nj] = __builtin_amdgcn_mfma_f32_16x16x32_bf16(aq0, bk0, accs[nj], 0, 0, 0);
      accs[nj] = __builtin_amdgcn_mfma_f32_16x16x32_bf16(aq1, bk1, accs[nj], 0, 0, 0);
    }
    // online softmax
    float sv[4][4];
    float tmax[4] = {-1e30f, -1e30f, -1e30f, -1e30f};
    for (int nj = 0; nj < 4; ++nj)
      for (int j = 0; j < 4; ++j) {
        float s = accs[nj][j];
        if (anyqp) s += qpv[nj][j];
        s *= SCALE;
        sv[nj][j] = s;
        tmax[j] = fmaxf(tmax[j], s);
      }
    for (int d = 1; d < 16; d <<= 1)
      for (int j = 0; j < 4; ++j) tmax[j] = fmaxf(tmax[j], __shfl_xor(tmax[j], d, 64));
    float sc[4], rsum[4];
    for (int j = 0; j < 4; ++j) {
      float mn = fmaxf(m[j], tmax[j]);
      sc[j] = __expf(m[j] - mn);
      m[j] = mn;
      rsum[j] = 0.f;
    }
    for (int nj = 0; nj < 4; ++nj)
      for (int j = 0; j < 4; ++j) {
        float p = __expf(sv[nj][j] - m[j]);
        rsum[j] += p;
        Ps[w][lg * 4 + j][nj * 16 + lr] = f2bf(p);
      }
    for (int d = 1; d < 16; d <<= 1)
      for (int j = 0; j < 4; ++j) rsum[j] += __shfl_xor(rsum[j], d, 64);
    for (int j = 0; j < 4; ++j) lsum[j] = lsum[j] * sc[j] + rsum[j];
    for (int n = 0; n < 4; ++n)
      for (int j = 0; j < 4; ++j) acc_o[n][j] *= sc[j];
    // drain this wave's Ps ds_writes before cross-lane ds_reads
    asm volatile("s_waitcnt lgkmcnt(0)" ::: "memory");
    __builtin_amdgcn_sched_barrier(0);
    // O += P @ V
    for (int ks = 0; ks < 2; ++ks) {
      bf16x8 ap = ld8(&Ps[w][lr][ks * 32 + lg * 8]);
      for (int n = 0; n < 4; ++n) {
        int row = n * 16 + lr;
        bf16x8 bv = ld8(&Vs[row * 64 + (((ks * 4 + lg) ^ (row & 7)) * 8)]);
        acc_o[n] = __builtin_amdgcn_mfma_f32_16x16x32_bf16(ap, bv, acc_o[n], 0, 0, 0);
      }
    }
  }
  for (int n = 0; n < 4; ++n)
    for (int j = 0; j < 4; ++j) {
      float v = acc_o[n][j] / lsum[j];
      obf[((long)(b * 1024 + rg + j)) * 1024 + h * 64 + n * 16 + lr] = f2bf(v);
    }
}

// ---------------- launcher ----------------
extern "C" void kernel_launch(void* const* d_in, const int* in_sizes, int n_in,
                              void* d_out, int out_size, void* d_ws, size_t ws_size,
                              hipStream_t stream) {
  const float* x       = (const float*)d_in[0];
  const float* mem     = (const float*)d_in[1];
  const float* pos_emb = (const float*)d_in[3];
  const float* Wq      = (const float*)d_in[5];
  const float* Wkv     = (const float*)d_in[6];
  const float* Wo      = (const float*)d_in[7];
  const float* bo      = (const float*)d_in[8];
  const float* conv_w  = (const float*)d_in[9];
  const float* conv_b  = (const float*)d_in[10];
  float* out = (float*)d_out;

  char* ws = (char*)d_ws;
  unsigned short* xb   = (unsigned short*)(ws + 0);         // 4 MB (reused as Vt after QKV gemm)
  unsigned short* Vt   = xb;
  unsigned short* WbT  = (unsigned short*)(ws + 4194304);   // 6 MB  [3072][1024]
  unsigned short* qkvb = (unsigned short*)(ws + 10485760);  // 12 MB [2048][3072]
  unsigned short* peb  = (unsigned short*)(ws + 23068672);  // 2 MB  [16][1024][64]
  unsigned short* obf  = (unsigned short*)(ws + 25165824);  // 4 MB  [2048][1024]
  unsigned short* WoT  = (unsigned short*)(ws + 29360128);  // 2 MB  [1024][1024]
  unsigned short* memb = (unsigned short*)(ws + 31457280);  // 4 MB  [512][4096]
  unsigned short* BcT  = (unsigned short*)(ws + 35651584);  // 8 MB  [1024][4096]
  unsigned short* QPbf = (unsigned short*)(ws + 44040192);  // 64 MB [2][16][1024][1024] (shifted)
  float* convpart = (float*)(ws + 44040192);                // 16 MB, reuses QP after attn

  float* logits   = out;                // 2097152
  float* new_mem  = out + 2097152;      // 2097152
  float* new_cmem = out + 4194304;      // 524288
  float* aux      = out + 4718592;      // 1

  // prep
  cast_x_mem<<<4096, 256, 0, stream>>>(x, mem, xb, memb, new_mem, aux);
  cast_pe<<<1024, 256, 0, stream>>>(pos_emb, peb);
  transpose3<<<dim3(64, 16), 256, 0, stream>>>(Wq, Wkv, Wo, WbT, WoT);
  convw_t<<<4096, 256, 0, stream>>>(conv_w, BcT);

  // qkv = xb @ WbT^T  (2048 x 3072 x 1024), BM=64 -> 768 blocks
  gemm_bt<2, false, false, false, false><<<dim3(24, 32, 1), 256, 0, stream>>>(
      xb, WbT, qkvb, nullptr, 1024, 1024, 1024, 3072, 1, 0, 0, 0, 0, 0, 0);

  // V transpose: qkvb -> Vt[b][h][d][t]  (overwrites dead xb region)
  vt_prep<<<dim3(16, 16, 2), 256, 0, stream>>>(qkvb, Vt);

  // QPs[b,h,r,cx] = (q[b,h] @ peb[h]^T) pre-shifted; skip below-band blocks
  gemm_bt<4, false, false, true, true><<<dim3(8, 8, 32), 256, 0, stream>>>(
      qkvb, peb, QPbf, nullptr, 64, 3072, 64, 1024,
      16, 3145728, 64, 0, 65536, 16777216, 1048576);

  // attention
  attn_kernel<<<dim3(16, 16, 2), 256, 0, stream>>>(qkvb, Vt, QPbf, obf);

  // logits = obf @ WoT^T + bo  (2048 x 1024 x 1024), BM=64 -> 256 blocks
  gemm_bt<2, true, true, false, false><<<dim3(8, 32, 1), 256, 0, stream>>>(
      obf, WoT, logits, bo, 1024, 1024, 1024, 1024, 1, 0, 0, 0, 0, 0, 0);

  // new_cmem partials: split-K x8 (512 blocks, K=512 each)
  gemm_bt<2, true, false, false, false><<<dim3(8, 8, 8), 256, 0, stream>>>(
      memb, BcT, convpart, nullptr, 512, 4096, 4096, 1024,
      1, 512, 0, 512, 0, 524288, 0);
  splitk_reduce_bias<<<512, 256, 0, stream>>>(convpart, conv_b, new_cmem);
}

// Round 6
// 264.308 us; speedup vs baseline: 1.7314x; 1.0212x over previous
//
#include <hip/hip_runtime.h>
#include <hip/hip_bf16.h>

typedef __bf16 bf16x8 __attribute__((ext_vector_type(8)));
typedef float f32x4 __attribute__((ext_vector_type(4)));

#define SCALE 0.125f

typedef __attribute__((address_space(1))) const unsigned int gas_u32;
typedef __attribute__((address_space(3))) unsigned int las_u32;

__device__ __forceinline__ void gload16(const void* g, void* l) {
  __builtin_amdgcn_global_load_lds((gas_u32*)g, (las_u32*)l, 16, 0, 0);
}

__device__ __forceinline__ unsigned short f2bf(float f) {
  unsigned int u = __float_as_uint(f);
  u = (u + 0x7fffu + ((u >> 16) & 1u)) >> 16;
  return (unsigned short)u;
}
__device__ __forceinline__ float bf2f(unsigned short s) {
  return __uint_as_float(((unsigned int)s) << 16);
}
__device__ __forceinline__ f32x4 f4zero() {
  f32x4 v; v[0] = 0.f; v[1] = 0.f; v[2] = 0.f; v[3] = 0.f; return v;
}
__device__ __forceinline__ bf16x8 ld8(const unsigned short* p) {
  return *(const bf16x8*)p;
}

// ---------------- prep kernels ----------------

// merged: x -> xb/new_mem/aux, mem -> memb
__global__ void cast_x_mem(const float* __restrict__ x, const float* __restrict__ mem,
                           unsigned short* __restrict__ xb, unsigned short* __restrict__ memb,
                           float* __restrict__ newmem, float* __restrict__ aux) {
  long i = (long)blockIdx.x * 256 + threadIdx.x;   // over float4, total 1048576
  if (i < 524288) {
    float4 v = ((const float4*)x)[i];
    ((float4*)newmem)[i] = v;
    ushort4 o; o.x = f2bf(v.x); o.y = f2bf(v.y); o.z = f2bf(v.z); o.w = f2bf(v.w);
    ((ushort4*)xb)[i] = o;
    if (i == 0) aux[0] = 0.f;
  } else {
    long j = i - 524288;
    float4 v = ((const float4*)mem)[j];
    ushort4 o; o.x = f2bf(v.x); o.y = f2bf(v.y); o.z = f2bf(v.z); o.w = f2bf(v.w);
    ((ushort4*)memb)[j] = o;
  }
}

// pos_emb[h,1280+u,d] -> peb[h][u][d] bf16
__global__ void cast_pe(const float* __restrict__ pe, unsigned short* __restrict__ peb) {
  long i = (long)blockIdx.x * 256 + threadIdx.x;   // over float4, total 262144
  int h = (int)(i >> 14);
  int rem = (int)(i & 16383);
  const float4* src = (const float4*)(pe + ((long)h * 2304 + 1280) * 64);
  float4 v = src[rem];
  ushort4 o; o.x = f2bf(v.x); o.y = f2bf(v.y); o.z = f2bf(v.z); o.w = f2bf(v.w);
  *(ushort4*)(peb + (long)h * 65536 + (long)rem * 4) = o;
}

// merged 3-way f32 (K x N) -> bf16 transpose (N x K): Wq, Wkv, Wo
__global__ void transpose3(const float* __restrict__ Wq, const float* __restrict__ Wkv,
                           const float* __restrict__ Wo,
                           unsigned short* __restrict__ WbT, unsigned short* __restrict__ WoT) {
  __shared__ float tile[64][65];
  int bx = blockIdx.x;
  const float* in; unsigned short* out; int N, bxl;
  if (bx < 16)      { in = Wq;  out = WbT;           N = 1024; bxl = bx; }
  else if (bx < 48) { in = Wkv; out = WbT + 1048576; N = 2048; bxl = bx - 16; }
  else              { in = Wo;  out = WoT;           N = 1024; bxl = bx - 48; }
  int k0 = blockIdx.y * 64, n0 = bxl * 64;
  int t = threadIdx.x;
  int c = t & 63, r4 = t >> 6;
  for (int rr = r4; rr < 64; rr += 4)
    tile[rr][c] = in[(long)(k0 + rr) * N + n0 + c];
  __syncthreads();
  for (int rr = r4; rr < 64; rr += 4)
    out[(long)(n0 + rr) * 1024 + k0 + c] = f2bf(tile[c][rr]);
}

// conv_w[o][i][kh] -> BcT[o][kh*1024+i] bf16
__global__ void convw_t(const float* __restrict__ cw, unsigned short* __restrict__ BcT) {
  long i = (long)blockIdx.x * 256 + threadIdx.x;   // total 1048576 = o*1024+ii
  int o = (int)(i >> 10), ii = (int)(i & 1023);
  float4 v = *(const float4*)&cw[i * 4];
  unsigned short* base = BcT + (long)o * 4096 + ii;
  base[0]    = f2bf(v.x);
  base[1024] = f2bf(v.y);
  base[2048] = f2bf(v.z);
  base[3072] = f2bf(v.w);
}

// qkvb v-section -> Vt[b][h][d][t] bf16
__global__ void vt_prep(const unsigned short* __restrict__ qkvb, unsigned short* __restrict__ Vt) {
  __shared__ unsigned short L[64][72];
  int tt = blockIdx.x, h = blockIdx.y, b = blockIdx.z;
  int t0 = tt * 64;
  int tid = threadIdx.x;
  int row = tid >> 2, ch = tid & 3;
  const unsigned short* src = qkvb + (long)(b * 1024 + t0 + row) * 3072 + 2048 + h * 64;
  *(uint4*)&L[row][ch * 8]       = *(const uint4*)&src[ch * 8];
  *(uint4*)&L[row][(ch + 4) * 8] = *(const uint4*)&src[(ch + 4) * 8];
  __syncthreads();
  int d = tid >> 2, tch = tid & 3;
  unsigned short* dst = Vt + ((long)((b * 16 + h) * 64 + d)) * 1024 + t0;
  for (int s = tch; s < 8; s += 4) {
    unsigned short tmp[8];
    for (int i = 0; i < 8; ++i) tmp[i] = L[s * 8 + i][d];
    *(uint4*)&dst[s * 8] = *(const uint4*)tmp;
  }
}

// sum 8 split-K partials + bias -> out (512x1024 f32)
__global__ void splitk_reduce_bias(const float* __restrict__ part,
                                   const float* __restrict__ bias,
                                   float* __restrict__ out) {
  int i = blockIdx.x * 256 + threadIdx.x;   // over float4, total 131072
  float4 a = ((const float4*)part)[i];
  for (int s = 1; s < 8; ++s) {
    float4 b = ((const float4*)(part + (long)s * 524288))[i];
    a.x += b.x; a.y += b.y; a.z += b.z; a.w += b.w;
  }
  float4 bb = *(const float4*)&bias[(i * 4) & 1023];
  a.x += bb.x; a.y += bb.y; a.z += bb.z; a.w += bb.w;
  ((float4*)out)[i] = a;
}

// ---------------- generic GEMM: C = A(MxK) @ BT(NxK)^T ----------------
// global_load_lds (16B) staging, linear LDS dest, XOR-swizzled 16B slots.
template<int M_REP, bool OUT_F32, bool HAS_BIAS>
__global__ __launch_bounds__(256) void gemm_bt(
    const unsigned short* __restrict__ A, const unsigned short* __restrict__ BT,
    void* __restrict__ Cout, const float* __restrict__ bias,
    int K, int lda, int ldbt, int ldc,
    int zInner, long sAo, long sAi, long sBo, long sBi, long sCo, long sCi) {
  constexpr int BM = 32 * M_REP;
  constexpr int ACH = BM / 16;          // 1KB chunks in As
  __shared__ unsigned short As[BM * 32];
  __shared__ unsigned short Bs[128 * 32];
  int z = blockIdx.z;
  int zo = z / zInner, zi = z % zInner;
  A += zo * sAo + zi * sAi;
  BT += zo * sBo + zi * sBi;
  long coff = zo * sCo + zi * sCi;
  int r0 = blockIdx.y * BM;
  int c0 = blockIdx.x * 128;
  int tid = threadIdx.x;
  int lane = tid & 63, wid = tid >> 6;
  int wm = wid >> 1, wn = wid & 1;
  int lr = lane & 15, lg = lane >> 4;
  int srow = lane >> 2;
  int sg8 = (((lane & 3) ^ ((lane >> 3) & 3)) * 8);

  f32x4 acc[M_REP][4];
  for (int mi = 0; mi < M_REP; ++mi)
    for (int nj = 0; nj < 4; ++nj) acc[mi][nj] = f4zero();

  int nK = K >> 5;
  for (int kt = 0; kt < nK; ++kt) {
    __syncthreads();
    for (int c = wid; c < ACH + 8; c += 4) {
      if (c < ACH) {
        int row = c * 16 + srow;
        gload16(&A[(long)(r0 + row) * lda + kt * 32 + sg8], As + c * 512);
      } else {
        int cb = c - ACH;
        int row = cb * 16 + srow;
        gload16(&BT[(long)(c0 + row) * ldbt + kt * 32 + sg8], Bs + cb * 512);
      }
    }
    __syncthreads();
    bf16x8 af[M_REP], bfr[4];
    for (int mi = 0; mi < M_REP; ++mi) {
      int row = wm * (16 * M_REP) + mi * 16 + lr;
      af[mi] = ld8(&As[row * 32 + ((lg ^ ((row >> 1) & 3)) * 8)]);
    }
    for (int nj = 0; nj < 4; ++nj) {
      int row = wn * 64 + nj * 16 + lr;
      bfr[nj] = ld8(&Bs[row * 32 + ((lg ^ ((row >> 1) & 3)) * 8)]);
    }
    for (int mi = 0; mi < M_REP; ++mi)
      for (int nj = 0; nj < 4; ++nj)
        acc[mi][nj] = __builtin_amdgcn_mfma_f32_16x16x32_bf16(af[mi], bfr[nj], acc[mi][nj], 0, 0, 0);
  }
  float* Cf = (float*)Cout;
  unsigned short* Cb = (unsigned short*)Cout;
  for (int mi = 0; mi < M_REP; ++mi)
    for (int nj = 0; nj < 4; ++nj)
      for (int j = 0; j < 4; ++j) {
        int r = r0 + wm * (16 * M_REP) + mi * 16 + lg * 4 + j;
        int c = c0 + wn * 64 + nj * 16 + lr;
        float v = acc[mi][nj][j];
        if (HAS_BIAS) v += bias[c];
        long off = coff + (long)r * ldc + c;
        if (OUT_F32) Cf[off] = v; else Cb[off] = f2bf(v);
      }
}

// ---------------- attention (rel-pos computed in-kernel via MFMA) ----------------
// grid (16 q-tiles, 16 heads, 2 batch), 256 threads (4 waves, 16 q-rows each)
__global__ __launch_bounds__(256) void attn_kernel(
    const unsigned short* __restrict__ qkv,   // [2048][3072] bf16: q|k|v
    const unsigned short* __restrict__ Vt,    // [b][h][d][1024] bf16
    const unsigned short* __restrict__ peb,   // [16][1024][64] bf16
    unsigned short* __restrict__ obf) {       // [2048][1024] bf16
  int rt = blockIdx.x, h = blockIdx.y, b = blockIdx.z;
  int tid = threadIdx.x;
  int lane = tid & 63, w = tid >> 6;
  int lr = lane & 15, lg = lane >> 4;
  int r0 = rt * 64;

  __shared__ unsigned short Ks[64 * 64];    // [cx][d], slot-swizzled
  __shared__ unsigned short Vs[64 * 64];    // [d][cx], slot-swizzled
  __shared__ unsigned short PEs[128 * 64];  // pe window [uu][d], slot-swizzled
  __shared__ float Sp[4][16][132];          // per-wave S_pos [q-row][uu], pad 132
  __shared__ unsigned short Ps[4][16][72];

  bf16x8 aq0, aq1;
  {
    const unsigned short* qrow = qkv + ((long)(b * 1024 + r0 + w * 16 + lr)) * 3072 + h * 64;
    aq0 = ld8(qrow + lg * 8);
    aq1 = ld8(qrow + 32 + lg * 8);
  }
  float m[4], lsum[4];
  f32x4 acc_o[4];
  for (int j = 0; j < 4; ++j) { m[j] = -1e30f; lsum[j] = 0.f; }
  for (int n = 0; n < 4; ++n) acc_o[n] = f4zero();

  const unsigned short* kbase = qkv + (long)b * 1024 * 3072 + 1024 + h * 64;
  const unsigned short* vtb = Vt + ((long)(b * 16 + h)) * 65536;
  const unsigned short* peh = peb + (long)h * 65536;
  int rg = r0 + w * 16 + lg * 4;   // + j = global q row

  int srow = (lane >> 3) & 7;   // row within 8-row chunk
  int sslot = lane & 7;         // dest 16B slot within row

  for (int kt = 0; kt < 16; ++kt) {
    int c0 = kt * 64;
    bool band = (kt <= rt);
    int ub = 960 + (kt - rt) * 64;   // pe window base (band tiles only)
    __syncthreads();
    for (int i = 0; i < 2; ++i) {
      int chunk = w * 2 + i;                 // 0..7 (8 rows each)
      int row = chunk * 8 + srow;            // 0..63
      int g = sslot ^ (row & 7);             // inverse swizzle at source
      gload16(&kbase[(long)(c0 + row) * 3072 + g * 8], Ks + chunk * 512);
      gload16(&vtb[(long)row * 1024 + c0 + g * 8], Vs + chunk * 512);
    }
    if (band) {
      for (int i = 0; i < 4; ++i) {
        int chunk = w * 4 + i;               // 0..15 (8 rows each)
        int prow = chunk * 8 + srow;         // 0..127
        int u = min(ub + prow, 1023);        // clamp (only hits invalid diag cols)
        int g = sslot ^ (prow & 7);
        gload16(&peh[(long)u * 64 + g * 8], PEs + chunk * 512);
      }
    }
    __syncthreads();
    // S = q @ k^T
    f32x4 accs[4];
    for (int nj = 0; nj < 4; ++nj) {
      int row = nj * 16 + lr;
      bf16x8 bk0 = ld8(&Ks[row * 64 + ((lg ^ (row & 7)) * 8)]);
      bf16x8 bk1 = ld8(&Ks[row * 64 + (((4 + lg) ^ (row & 7)) * 8)]);
      accs[nj] = f4zero();
      accs[nj] = __builtin_amdgcn_mfma_f32_16x16x32_bf16(aq0, bk0, accs[nj], 0, 0, 0);
      accs[nj] = __builtin_amdgcn_mfma_f32_16x16x32_bf16(aq1, bk1, accs[nj], 0, 0, 0);
    }
    // S_pos = q @ pe_window^T, then diagonal gather through LDS
    float qpv[4][4];
    if (band) {
      f32x4 accp[8];
      for (int p = 0; p < 8; ++p) {
        int prow = p * 16 + lr;
        bf16x8 pe0 = ld8(&PEs[prow * 64 + ((lg ^ (prow & 7)) * 8)]);
        bf16x8 pe1 = ld8(&PEs[prow * 64 + (((4 + lg) ^ (prow & 7)) * 8)]);
        accp[p] = f4zero();
        accp[p] = __builtin_amdgcn_mfma_f32_16x16x32_bf16(aq0, pe0, accp[p], 0, 0, 0);
        accp[p] = __builtin_amdgcn_mfma_f32_16x16x32_bf16(aq1, pe1, accp[p], 0, 0, 0);
      }
      for (int p = 0; p < 8; ++p)
        for (int j = 0; j < 4; ++j)
          Sp[w][lg * 4 + j][p * 16 + lr] = accp[p][j];
      asm volatile("s_waitcnt lgkmcnt(0)" ::: "memory");
      __builtin_amdgcn_sched_barrier(0);
      for (int nj = 0; nj < 4; ++nj)
        for (int j = 0; j < 4; ++j) {
          int uu = nj * 16 + lr - lg * 4 - j + 63;   // in [48,126]
          bool valid = (kt < rt) || (uu <= 63);
          qpv[nj][j] = valid ? Sp[w][lg * 4 + j][uu] : 0.f;
        }
    }
    // online softmax
    float sv[4][4];
    float tmax[4] = {-1e30f, -1e30f, -1e30f, -1e30f};
    for (int nj = 0; nj < 4; ++nj)
      for (int j = 0; j < 4; ++j) {
        float s = accs[nj][j];
        if (band) s += qpv[nj][j];
        s *= SCALE;
        sv[nj][j] = s;
        tmax[j] = fmaxf(tmax[j], s);
      }
    for (int d = 1; d < 16; d <<= 1)
      for (int j = 0; j < 4; ++j) tmax[j] = fmaxf(tmax[j], __shfl_xor(tmax[j], d, 64));
    float sc[4], rsum[4];
    for (int j = 0; j < 4; ++j) {
      float mn = fmaxf(m[j], tmax[j]);
      sc[j] = __expf(m[j] - mn);
      m[j] = mn;
      rsum[j] = 0.f;
    }
    for (int nj = 0; nj < 4; ++nj)
      for (int j = 0; j < 4; ++j) {
        float p = __expf(sv[nj][j] - m[j]);
        rsum[j] += p;
        Ps[w][lg * 4 + j][nj * 16 + lr] = f2bf(p);
      }
    for (int d = 1; d < 16; d <<= 1)
      for (int j = 0; j < 4; ++j) rsum[j] += __shfl_xor(rsum[j], d, 64);
    for (int j = 0; j < 4; ++j) lsum[j] = lsum[j] * sc[j] + rsum[j];
    for (int n = 0; n < 4; ++n)
      for (int j = 0; j < 4; ++j) acc_o[n][j] *= sc[j];
    // drain this wave's Ps ds_writes before cross-lane ds_reads
    asm volatile("s_waitcnt lgkmcnt(0)" ::: "memory");
    __builtin_amdgcn_sched_barrier(0);
    // O += P @ V
    for (int ks = 0; ks < 2; ++ks) {
      bf16x8 ap = ld8(&Ps[w][lr][ks * 32 + lg * 8]);
      for (int n = 0; n < 4; ++n) {
        int row = n * 16 + lr;
        bf16x8 bv = ld8(&Vs[row * 64 + (((ks * 4 + lg) ^ (row & 7)) * 8)]);
        acc_o[n] = __builtin_amdgcn_mfma_f32_16x16x32_bf16(ap, bv, acc_o[n], 0, 0, 0);
      }
    }
  }
  for (int n = 0; n < 4; ++n)
    for (int j = 0; j < 4; ++j) {
      float v = acc_o[n][j] / lsum[j];
      obf[((long)(b * 1024 + rg + j)) * 1024 + h * 64 + n * 16 + lr] = f2bf(v);
    }
}

// ---------------- launcher ----------------
extern "C" void kernel_launch(void* const* d_in, const int* in_sizes, int n_in,
                              void* d_out, int out_size, void* d_ws, size_t ws_size,
                              hipStream_t stream) {
  const float* x       = (const float*)d_in[0];
  const float* mem     = (const float*)d_in[1];
  const float* pos_emb = (const float*)d_in[3];
  const float* Wq      = (const float*)d_in[5];
  const float* Wkv     = (const float*)d_in[6];
  const float* Wo      = (const float*)d_in[7];
  const float* bo      = (const float*)d_in[8];
  const float* conv_w  = (const float*)d_in[9];
  const float* conv_b  = (const float*)d_in[10];
  float* out = (float*)d_out;

  char* ws = (char*)d_ws;
  unsigned short* xb   = (unsigned short*)(ws + 0);         // 4 MB (reused as Vt after QKV gemm)
  unsigned short* Vt   = xb;
  unsigned short* WbT  = (unsigned short*)(ws + 4194304);   // 6 MB  [3072][1024]
  unsigned short* qkvb = (unsigned short*)(ws + 10485760);  // 12 MB [2048][3072]
  unsigned short* peb  = (unsigned short*)(ws + 23068672);  // 2 MB  [16][1024][64]
  unsigned short* obf  = (unsigned short*)(ws + 25165824);  // 4 MB  [2048][1024]
  unsigned short* WoT  = (unsigned short*)(ws + 29360128);  // 2 MB  [1024][1024]
  unsigned short* memb = (unsigned short*)(ws + 31457280);  // 4 MB  [512][4096]
  unsigned short* BcT  = (unsigned short*)(ws + 35651584);  // 8 MB  [1024][4096]
  float* convpart = (float*)(ws + 44040192);                // 16 MB split-K partials

  float* logits   = out;                // 2097152
  float* new_mem  = out + 2097152;      // 2097152
  float* new_cmem = out + 4194304;      // 524288
  float* aux      = out + 4718592;      // 1

  // prep
  cast_x_mem<<<4096, 256, 0, stream>>>(x, mem, xb, memb, new_mem, aux);
  cast_pe<<<1024, 256, 0, stream>>>(pos_emb, peb);
  transpose3<<<dim3(64, 16), 256, 0, stream>>>(Wq, Wkv, Wo, WbT, WoT);
  convw_t<<<4096, 256, 0, stream>>>(conv_w, BcT);

  // qkv = xb @ WbT^T  (2048 x 3072 x 1024), 128^2 tiles -> 384 blocks
  gemm_bt<4, false, false><<<dim3(24, 16, 1), 256, 0, stream>>>(
      xb, WbT, qkvb, nullptr, 1024, 1024, 1024, 3072, 1, 0, 0, 0, 0, 0, 0);

  // V transpose: qkvb -> Vt[b][h][d][t]  (overwrites dead xb region)
  vt_prep<<<dim3(16, 16, 2), 256, 0, stream>>>(qkvb, Vt);

  // attention (rel-pos in-kernel)
  attn_kernel<<<dim3(16, 16, 2), 256, 0, stream>>>(qkvb, Vt, peb, obf);

  // logits = obf @ WoT^T + bo  (2048 x 1024 x 1024), 128^2 -> 128 blocks
  gemm_bt<4, true, true><<<dim3(8, 16, 1), 256, 0, stream>>>(
      obf, WoT, logits, bo, 1024, 1024, 1024, 1024, 1, 0, 0, 0, 0, 0, 0);

  // new_cmem partials: split-K x8 (256 blocks, K=512 each), 128^2 tiles
  gemm_bt<4, true, false><<<dim3(8, 4, 8), 256, 0, stream>>>(
      memb, BcT, convpart, nullptr, 512, 4096, 4096, 1024,
      1, 512, 0, 512, 0, 524288, 0);
  splitk_reduce_bias<<<512, 256, 0, stream>>>(convpart, conv_b, new_cmem);
}

// Round 7
// 242.485 us; speedup vs baseline: 1.8872x; 1.0900x over previous
//
#include <hip/hip_runtime.h>
#include <hip/hip_bf16.h>

typedef __bf16 bf16x8 __attribute__((ext_vector_type(8)));
typedef float f32x4 __attribute__((ext_vector_type(4)));

#define SCALE 0.125f
#define MFMA16 __builtin_amdgcn_mfma_f32_16x16x32_bf16

typedef __attribute__((address_space(1))) const unsigned int gas_u32;
typedef __attribute__((address_space(3))) unsigned int las_u32;

__device__ __forceinline__ void gload16(const void* g, void* l) {
  __builtin_amdgcn_global_load_lds((gas_u32*)g, (las_u32*)l, 16, 0, 0);
}

__device__ __forceinline__ unsigned short f2bf(float f) {
  unsigned int u = __float_as_uint(f);
  u = (u + 0x7fffu + ((u >> 16) & 1u)) >> 16;
  return (unsigned short)u;
}
__device__ __forceinline__ f32x4 f4zero() {
  f32x4 v; v[0] = 0.f; v[1] = 0.f; v[2] = 0.f; v[3] = 0.f; return v;
}
__device__ __forceinline__ bf16x8 ld8(const unsigned short* p) {
  return *(const bf16x8*)p;
}

// ---------------- merged prep kernel ----------------
// blocks [0,4096): x->xb/new_mem/aux + mem->memb
// blocks [4096,5120): pos_emb window -> peb
// blocks [5120,9216): conv_w -> BcT
// blocks [9216,10240): Wq/Wkv/Wo f32 transpose -> bf16 WbT/WoT
__global__ void prep_all(const float* __restrict__ x, const float* __restrict__ mem,
                         const float* __restrict__ pe,
                         const float* __restrict__ Wq, const float* __restrict__ Wkv,
                         const float* __restrict__ Wo, const float* __restrict__ cw,
                         unsigned short* __restrict__ xb, unsigned short* __restrict__ memb,
                         float* __restrict__ newmem, float* __restrict__ aux,
                         unsigned short* __restrict__ peb,
                         unsigned short* __restrict__ WbT, unsigned short* __restrict__ WoT,
                         unsigned short* __restrict__ BcT) {
  __shared__ float tile[64][65];
  int bx = blockIdx.x;
  int tid = threadIdx.x;
  if (bx < 4096) {
    long i = (long)bx * 256 + tid;   // over float4, total 1048576
    if (i < 524288) {
      float4 v = ((const float4*)x)[i];
      ((float4*)newmem)[i] = v;
      ushort4 o; o.x = f2bf(v.x); o.y = f2bf(v.y); o.z = f2bf(v.z); o.w = f2bf(v.w);
      ((ushort4*)xb)[i] = o;
      if (i == 0) aux[0] = 0.f;
    } else {
      long j = i - 524288;
      float4 v = ((const float4*)mem)[j];
      ushort4 o; o.x = f2bf(v.x); o.y = f2bf(v.y); o.z = f2bf(v.z); o.w = f2bf(v.w);
      ((ushort4*)memb)[j] = o;
    }
  } else if (bx < 5120) {
    long i = (long)(bx - 4096) * 256 + tid;   // over float4, total 262144
    int h = (int)(i >> 14);
    int rem = (int)(i & 16383);
    const float4* src = (const float4*)(pe + ((long)h * 2304 + 1280) * 64);
    float4 v = src[rem];
    ushort4 o; o.x = f2bf(v.x); o.y = f2bf(v.y); o.z = f2bf(v.z); o.w = f2bf(v.w);
    *(ushort4*)(peb + (long)h * 65536 + (long)rem * 4) = o;
  } else if (bx < 9216) {
    long i = (long)(bx - 5120) * 256 + tid;   // total 1048576 = o*1024+ii
    int o = (int)(i >> 10), ii = (int)(i & 1023);
    float4 v = *(const float4*)&cw[i * 4];
    unsigned short* base = BcT + (long)o * 4096 + ii;
    base[0]    = f2bf(v.x);
    base[1024] = f2bf(v.y);
    base[2048] = f2bf(v.z);
    base[3072] = f2bf(v.w);
  } else {
    int t = bx - 9216;           // 0..1023
    int bxt = t & 63, byt = t >> 6;
    const float* in; unsigned short* outp; int N, bxl;
    if (bxt < 16)      { in = Wq;  outp = WbT;           N = 1024; bxl = bxt; }
    else if (bxt < 48) { in = Wkv; outp = WbT + 1048576; N = 2048; bxl = bxt - 16; }
    else               { in = Wo;  outp = WoT;           N = 1024; bxl = bxt - 48; }
    int k0 = byt * 64, n0 = bxl * 64;
    int c = tid & 63, r4 = tid >> 6;
    for (int rr = r4; rr < 64; rr += 4)
      tile[rr][c] = in[(long)(k0 + rr) * N + n0 + c];
    __syncthreads();
    for (int rr = r4; rr < 64; rr += 4)
      outp[(long)(n0 + rr) * 1024 + k0 + c] = f2bf(tile[c][rr]);
  }
}

// qkvb v-section -> Vt[b][h][d][t] bf16
__global__ void vt_prep(const unsigned short* __restrict__ qkvb, unsigned short* __restrict__ Vt) {
  __shared__ unsigned short L[64][72];
  int tt = blockIdx.x, h = blockIdx.y, b = blockIdx.z;
  int t0 = tt * 64;
  int tid = threadIdx.x;
  int row = tid >> 2, ch = tid & 3;
  const unsigned short* src = qkvb + (long)(b * 1024 + t0 + row) * 3072 + 2048 + h * 64;
  *(uint4*)&L[row][ch * 8]       = *(const uint4*)&src[ch * 8];
  *(uint4*)&L[row][(ch + 4) * 8] = *(const uint4*)&src[(ch + 4) * 8];
  __syncthreads();
  int d = tid >> 2, tch = tid & 3;
  unsigned short* dst = Vt + ((long)((b * 16 + h) * 64 + d)) * 1024 + t0;
  for (int s = tch; s < 8; s += 4) {
    unsigned short tmp[8];
    for (int i = 0; i < 8; ++i) tmp[i] = L[s * 8 + i][d];
    *(uint4*)&dst[s * 8] = *(const uint4*)tmp;
  }
}

// sum 8 split-K partials + bias -> out (512x1024 f32)
__global__ void splitk_reduce_bias(const float* __restrict__ part,
                                   const float* __restrict__ bias,
                                   float* __restrict__ out) {
  int i = blockIdx.x * 256 + threadIdx.x;   // over float4, total 131072
  float4 a = ((const float4*)part)[i];
  for (int s = 1; s < 8; ++s) {
    float4 b = ((const float4*)(part + (long)s * 524288))[i];
    a.x += b.x; a.y += b.y; a.z += b.z; a.w += b.w;
  }
  float4 bb = *(const float4*)&bias[(i * 4) & 1023];
  a.x += bb.x; a.y += bb.y; a.z += bb.z; a.w += bb.w;
  ((float4*)out)[i] = a;
}

// ---------------- generic GEMM: C = A(MxK) @ BT(NxK)^T ----------------
// 2-phase prefetch: issue global_load_lds for tile kt+1 before computing kt;
// single vmcnt(0)+barrier per K-step. Linear LDS dest + bijective slot XOR.
template<int M_REP, bool OUT_F32, bool HAS_BIAS>
__global__ __launch_bounds__(256) void gemm_bt(
    const unsigned short* __restrict__ A, const unsigned short* __restrict__ BT,
    void* __restrict__ Cout, const float* __restrict__ bias,
    int K, int lda, int ldbt, int ldc,
    int zInner, long sAo, long sAi, long sBo, long sBi, long sCo, long sCi) {
  constexpr int BM = 32 * M_REP;
  constexpr int ACH = BM / 16;          // 1KB chunks in As
  constexpr int ABUF = BM * 32;         // ushorts per A buffer
  __shared__ unsigned short As[2 * ABUF];
  __shared__ unsigned short Bs[2 * 4096];
  int z = blockIdx.z;
  int zo = z / zInner, zi = z % zInner;
  A += zo * sAo + zi * sAi;
  BT += zo * sBo + zi * sBi;
  long coff = zo * sCo + zi * sCi;
  int r0 = blockIdx.y * BM;
  int c0 = blockIdx.x * 128;
  int tid = threadIdx.x;
  int lane = tid & 63, wid = tid >> 6;
  int wm = wid >> 1, wn = wid & 1;
  int lr = lane & 15, lg = lane >> 4;
  int srow = lane >> 2;
  int sg8 = (((lane & 3) ^ ((lane >> 3) & 3)) * 8);

  auto stage = [&](int kt, int buf) {
    for (int c = wid; c < ACH + 8; c += 4) {
      if (c < ACH) {
        gload16(&A[(long)(r0 + c * 16 + srow) * lda + kt * 32 + sg8],
                As + buf * ABUF + c * 512);
      } else {
        int cb = c - ACH;
        gload16(&BT[(long)(c0 + cb * 16 + srow) * ldbt + kt * 32 + sg8],
                Bs + buf * 4096 + cb * 512);
      }
    }
  };

  f32x4 acc[M_REP][4];
  #pragma unroll
  for (int mi = 0; mi < M_REP; ++mi)
    #pragma unroll
    for (int nj = 0; nj < 4; ++nj) acc[mi][nj] = f4zero();

  int nK = K >> 5;
  stage(0, 0);
  asm volatile("s_waitcnt vmcnt(0)" ::: "memory");
  __syncthreads();
  for (int kt = 0; kt < nK; ++kt) {
    int cur = kt & 1;
    if (kt + 1 < nK) stage(kt + 1, cur ^ 1);
    bf16x8 af[M_REP], bfr[4];
    #pragma unroll
    for (int mi = 0; mi < M_REP; ++mi) {
      int row = wm * (16 * M_REP) + mi * 16 + lr;
      af[mi] = ld8(&As[cur * ABUF + row * 32 + ((lg ^ ((row >> 1) & 3)) * 8)]);
    }
    #pragma unroll
    for (int nj = 0; nj < 4; ++nj) {
      int row = wn * 64 + nj * 16 + lr;
      bfr[nj] = ld8(&Bs[cur * 4096 + row * 32 + ((lg ^ ((row >> 1) & 3)) * 8)]);
    }
    #pragma unroll
    for (int mi = 0; mi < M_REP; ++mi)
      #pragma unroll
      for (int nj = 0; nj < 4; ++nj)
        acc[mi][nj] = MFMA16(af[mi], bfr[nj], acc[mi][nj], 0, 0, 0);
    if (kt + 1 < nK) {
      asm volatile("s_waitcnt vmcnt(0)" ::: "memory");
      __syncthreads();
    }
  }
  float* Cf = (float*)Cout;
  unsigned short* Cb = (unsigned short*)Cout;
  #pragma unroll
  for (int mi = 0; mi < M_REP; ++mi)
    #pragma unroll
    for (int nj = 0; nj < 4; ++nj)
      #pragma unroll
      for (int j = 0; j < 4; ++j) {
        int r = r0 + wm * (16 * M_REP) + mi * 16 + lg * 4 + j;
        int c = c0 + wn * 64 + nj * 16 + lr;
        float v = acc[mi][nj][j];
        if (HAS_BIAS) v += bias[c];
        long off = coff + (long)r * ldc + c;
        if (OUT_F32) Cf[off] = v; else Cb[off] = f2bf(v);
      }
}

// ---------------- attention ----------------
// grid 512 blocks (XCD-swizzled), 256 threads (4 waves, 16 q-rows each).
// Rel-pos S_pos computed in-kernel via MFMA on a sliding 128-row pe window:
// per-wave local accp[5] quads (pl = p-(3-w)), carried across tiles
// (accp[0] <- accp[4]); diagonal gather via __shfl (static reg indices).
__global__ __launch_bounds__(256) void attn_kernel(
    const unsigned short* __restrict__ qkv,   // [2048][3072] bf16: q|k|v
    const unsigned short* __restrict__ Vt,    // [b][h][d][1024] bf16
    const unsigned short* __restrict__ peb,   // [16][1024][64] bf16
    unsigned short* __restrict__ obf) {       // [2048][1024] bf16
  int bid = blockIdx.x;
  int sw = ((bid & 7) << 6) | (bid >> 3);     // XCD-contiguous chunks
  int rt = sw & 15, h = (sw >> 4) & 15, b = sw >> 8;
  int tid = threadIdx.x;
  int lane = tid & 63, w = tid >> 6;
  int lr = lane & 15, lg = lane >> 4;
  int r0 = rt * 64;

  __shared__ unsigned short Ks[2 * 4096];   // dbuf [cx][d], slot-swizzled
  __shared__ unsigned short Vs[2 * 4096];   // dbuf [d][cx], slot-swizzled
  __shared__ unsigned short PEs[3 * 4096];  // 3-slot ring of 64-row pe blocks
  __shared__ unsigned short Ps[4][16][72];  // per-wave P tile

  bf16x8 aq0, aq1;
  {
    const unsigned short* qrow = qkv + ((long)(b * 1024 + r0 + w * 16 + lr)) * 3072 + h * 64;
    aq0 = ld8(qrow + lg * 8);
    aq1 = ld8(qrow + 32 + lg * 8);
  }
  float m[4], lsum[4];
  f32x4 acc_o[4], accp[5];
  #pragma unroll
  for (int j = 0; j < 4; ++j) { m[j] = -1e30f; lsum[j] = 0.f; }
  #pragma unroll
  for (int n = 0; n < 4; ++n) acc_o[n] = f4zero();

  const unsigned short* kbase = qkv + (long)b * 3145728 + 1024 + h * 64;
  const unsigned short* vtb = Vt + ((long)(b * 16 + h)) * 65536;
  const unsigned short* peh = peb + (long)h * 65536;
  int rg = r0 + w * 16 + lg * 4;   // + j = global q row
  int qq = w * 16 + lg * 4;        // + j = row within q-tile

  int srow = (lane >> 3) & 7;   // row within 8-row chunk
  int sslot = lane & 7;         // dest 16B slot within row

  auto stageKV = [&](int kt, int buf) {
    int c0 = kt * 64;
    #pragma unroll
    for (int i = 0; i < 2; ++i) {
      int chunk = w * 2 + i;
      int row = chunk * 8 + srow;
      int g = sslot ^ (row & 7);
      gload16(&kbase[(long)(c0 + row) * 3072 + g * 8], Ks + buf * 4096 + chunk * 512);
      gload16(&vtb[(long)row * 1024 + c0 + g * 8], Vs + buf * 4096 + chunk * 512);
    }
  };
  auto stagePE = [&](int blk) {
    int slot = blk % 3;
    #pragma unroll
    for (int i = 0; i < 2; ++i) {
      int chunk = w * 2 + i;
      int row = chunk * 8 + srow;
      int u = min(blk * 64 + row, 1023);
      int g = sslot ^ (row & 7);
      gload16(&peh[(long)u * 64 + g * 8], PEs + slot * 4096 + chunk * 512);
    }
  };
  auto peMFMA = [&](int pl, int ub) -> f32x4 {
    int u = min(ub + 48 - w * 16 + pl * 16 + lr, 1023);
    int off = ((u >> 6) % 3) * 4096 + (u & 63) * 64;
    bf16x8 p0 = ld8(&PEs[off + ((lg ^ (u & 7)) * 8)]);
    bf16x8 p1 = ld8(&PEs[off + (((4 + lg) ^ (u & 7)) * 8)]);
    f32x4 r = f4zero();
    r = MFMA16(aq0, p0, r, 0, 0, 0);
    r = MFMA16(aq1, p1, r, 0, 0, 0);
    return r;
  };

  // prologue: stage tile 0 K/V + both pe blocks of window 0
  stageKV(0, 0);
  stagePE(15 - rt);
  stagePE(16 - rt);
  asm volatile("s_waitcnt vmcnt(0)" ::: "memory");
  __syncthreads();

  for (int kt = 0; kt < 16; ++kt) {
    int cur = kt & 1;
    bool band = (kt <= rt);
    int ub = 960 + (kt - rt) * 64;
    // prefetch next tile
    if (kt < 15) stageKV(kt + 1, cur ^ 1);
    if (kt + 1 <= rt) stagePE(17 + kt - rt);
    // S = q @ k^T
    f32x4 accs[4];
    #pragma unroll
    for (int nj = 0; nj < 4; ++nj) {
      int row = nj * 16 + lr;
      const unsigned short* kb = &Ks[cur * 4096 + row * 64];
      bf16x8 bk0 = ld8(&kb[(lg ^ (row & 7)) * 8]);
      bf16x8 bk1 = ld8(&kb[((4 + lg) ^ (row & 7)) * 8]);
      accs[nj] = f4zero();
      accs[nj] = MFMA16(aq0, bk0, accs[nj], 0, 0, 0);
      accs[nj] = MFMA16(aq1, bk1, accs[nj], 0, 0, 0);
    }
    // S_pos quads + diagonal gather via shfl
    float qpv[4][4];
    if (band) {
      if (kt == 0) {
        #pragma unroll
        for (int pl = 0; pl < 5; ++pl) accp[pl] = peMFMA(pl, ub);
      } else {
        #pragma unroll
        for (int pl = 1; pl < 5; ++pl) accp[pl] = peMFMA(pl, ub);
      }
      #pragma unroll
      for (int j = 0; j < 4; ++j) {
        int sl = (lane & 48) | ((lr - lg * 4 - j - 1) & 15);
        bool hi = lr > lg * 4 + j;
        #pragma unroll
        for (int nj = 0; nj < 4; ++nj) {
          float vlo = __shfl(accp[nj][j], sl, 64);
          float vhi = __shfl(accp[nj + 1][j], sl, 64);
          float v = hi ? vhi : vlo;
          if (kt == rt) {
            int uu = nj * 16 + lr + 63 - (qq + j);
            if (uu > 63) v = 0.f;
          }
          qpv[nj][j] = v;
        }
      }
      accp[0] = accp[4];   // carry for next tile
    }
    // online softmax
    float sv[4][4];
    float tmax[4] = {-1e30f, -1e30f, -1e30f, -1e30f};
    #pragma unroll
    for (int nj = 0; nj < 4; ++nj)
      #pragma unroll
      for (int j = 0; j < 4; ++j) {
        float s = accs[nj][j];
        if (band) s += qpv[nj][j];
        s *= SCALE;
        sv[nj][j] = s;
        tmax[j] = fmaxf(tmax[j], s);
      }
    for (int d = 1; d < 16; d <<= 1)
      #pragma unroll
      for (int j = 0; j < 4; ++j) tmax[j] = fmaxf(tmax[j], __shfl_xor(tmax[j], d, 64));
    float sc[4], rsum[4];
    #pragma unroll
    for (int j = 0; j < 4; ++j) {
      float mn = fmaxf(m[j], tmax[j]);
      sc[j] = __expf(m[j] - mn);
      m[j] = mn;
      rsum[j] = 0.f;
    }
    #pragma unroll
    for (int nj = 0; nj < 4; ++nj)
      #pragma unroll
      for (int j = 0; j < 4; ++j) {
        float p = __expf(sv[nj][j] - m[j]);
        rsum[j] += p;
        Ps[w][lg * 4 + j][nj * 16 + lr] = f2bf(p);
      }
    for (int d = 1; d < 16; d <<= 1)
      #pragma unroll
      for (int j = 0; j < 4; ++j) rsum[j] += __shfl_xor(rsum[j], d, 64);
    #pragma unroll
    for (int j = 0; j < 4; ++j) lsum[j] = lsum[j] * sc[j] + rsum[j];
    #pragma unroll
    for (int n = 0; n < 4; ++n)
      #pragma unroll
      for (int j = 0; j < 4; ++j) acc_o[n][j] *= sc[j];
    // drain this wave's Ps ds_writes before cross-lane ds_reads
    asm volatile("s_waitcnt lgkmcnt(0)" ::: "memory");
    __builtin_amdgcn_sched_barrier(0);
    // O += P @ V
    #pragma unroll
    for (int ks = 0; ks < 2; ++ks) {
      bf16x8 ap = ld8(&Ps[w][lr][ks * 32 + lg * 8]);
      #pragma unroll
      for (int n = 0; n < 4; ++n) {
        int row = n * 16 + lr;
        bf16x8 bv = ld8(&Vs[cur * 4096 + row * 64 + (((ks * 4 + lg) ^ (row & 7)) * 8)]);
        acc_o[n] = MFMA16(ap, bv, acc_o[n], 0, 0, 0);
      }
    }
    if (kt < 15) {
      asm volatile("s_waitcnt vmcnt(0)" ::: "memory");
      __syncthreads();
    }
  }
  #pragma unroll
  for (int n = 0; n < 4; ++n)
    #pragma unroll
    for (int j = 0; j < 4; ++j) {
      float v = acc_o[n][j] / lsum[j];
      obf[((long)(b * 1024 + rg + j)) * 1024 + h * 64 + n * 16 + lr] = f2bf(v);
    }
}

// ---------------- launcher ----------------
extern "C" void kernel_launch(void* const* d_in, const int* in_sizes, int n_in,
                              void* d_out, int out_size, void* d_ws, size_t ws_size,
                              hipStream_t stream) {
  const float* x       = (const float*)d_in[0];
  const float* mem     = (const float*)d_in[1];
  const float* pos_emb = (const float*)d_in[3];
  const float* Wq      = (const float*)d_in[5];
  const float* Wkv     = (const float*)d_in[6];
  const float* Wo      = (const float*)d_in[7];
  const float* bo      = (const float*)d_in[8];
  const float* conv_w  = (const float*)d_in[9];
  const float* conv_b  = (const float*)d_in[10];
  float* out = (float*)d_out;

  char* ws = (char*)d_ws;
  unsigned short* xb   = (unsigned short*)(ws + 0);         // 4 MB (reused as Vt after QKV gemm)
  unsigned short* Vt   = xb;
  unsigned short* WbT  = (unsigned short*)(ws + 4194304);   // 6 MB  [3072][1024]
  unsigned short* qkvb = (unsigned short*)(ws + 10485760);  // 12 MB [2048][3072]
  unsigned short* peb  = (unsigned short*)(ws + 23068672);  // 2 MB  [16][1024][64]
  unsigned short* obf  = (unsigned short*)(ws + 25165824);  // 4 MB  [2048][1024]
  unsigned short* WoT  = (unsigned short*)(ws + 29360128);  // 2 MB  [1024][1024]
  unsigned short* memb = (unsigned short*)(ws + 31457280);  // 4 MB  [512][4096]
  unsigned short* BcT  = (unsigned short*)(ws + 35651584);  // 8 MB  [1024][4096]
  float* convpart = (float*)(ws + 44040192);                // 16 MB split-K partials

  float* logits   = out;                // 2097152
  float* new_mem  = out + 2097152;      // 2097152
  float* new_cmem = out + 4194304;      // 524288
  float* aux      = out + 4718592;      // 1

  // merged prep
  prep_all<<<10240, 256, 0, stream>>>(x, mem, pos_emb, Wq, Wkv, Wo, conv_w,
                                      xb, memb, new_mem, aux, peb, WbT, WoT, BcT);

  // qkv = xb @ WbT^T  (2048 x 3072 x 1024), BM=64 -> 768 blocks
  gemm_bt<2, false, false><<<dim3(24, 32, 1), 256, 0, stream>>>(
      xb, WbT, qkvb, nullptr, 1024, 1024, 1024, 3072, 1, 0, 0, 0, 0, 0, 0);

  // V transpose: qkvb -> Vt[b][h][d][t]  (overwrites dead xb region)
  vt_prep<<<dim3(16, 16, 2), 256, 0, stream>>>(qkvb, Vt);

  // attention (rel-pos in-kernel, carried accp, prefetched)
  attn_kernel<<<dim3(512, 1, 1), 256, 0, stream>>>(qkvb, Vt, peb, obf);

  // logits = obf @ WoT^T + bo  (2048 x 1024 x 1024), BM=64 -> 256 blocks
  gemm_bt<2, true, true><<<dim3(8, 32, 1), 256, 0, stream>>>(
      obf, WoT, logits, bo, 1024, 1024, 1024, 1024, 1, 0, 0, 0, 0, 0, 0);

  // new_cmem partials: split-K x8 (512 blocks, K=512 each)
  gemm_bt<2, true, false><<<dim3(8, 8, 8), 256, 0, stream>>>(
      memb, BcT, convpart, nullptr, 512, 4096, 4096, 1024,
      1, 512, 0, 512, 0, 524288, 0);
  splitk_reduce_bias<<<512, 256, 0, stream>>>(convpart, conv_b, new_cmem);
}